// Round 3
// baseline (540.328 us; speedup 1.0000x reference)
//
#include <hip/hip_runtime.h>
#include <hip/hip_cooperative_groups.h>
namespace cg = cooperative_groups;

// NeuralMapCell — ROUND 18. Theory: ~200us of the 350 is launch/drain gaps
// across 10 serial dispatches, not device work (kernel-sum model ~130us).
// Fix: ONE cooperative kernel, 256 blocks x 256 thr (1 block/CU, 50KB LDS),
// 6 grid.sync()s. conv2 staging sums the 8 conv1 chunk-partials (c1red
// kernel gone); softmax folded into ctp (exact block-max + reassociated
// denominator); transpose co-scheduled with r1p on idle blocks. Fallback:
// R17 multi-kernel path if cooperative launch is rejected.
//
// d_out = float[1049088]: c_t[256] r_t[256] new_mem[1048576].
// c1p (conv1 chunk partials, 8x32x4096) lives in out+512 (new_mem region),
// dead after conv2; transpose/final overwrite it with the real new_mem.
// All other intermediates in d_ws (poison-filled by harness; fully
// overwritten before read). ws float offsets:
#define W_C2   0          // 246016  conv2 out
#define W_P1   246016     // 119168  r1 partials (931 x 128)
#define W_RT   365184     // 256
#define W_QT   365440     // 256
#define W_ST   365696     // 256
#define W_SC   365952     // 4096   scores
#define W_PC   370048     // 16384  ct partials (64 x 256)
#define W_STAT 386432     // 512    per-block (max, expsum) pairs
#define W_END  386944

#define FLAT  238144      // 64*61*61
#define NB_R1 931

__device__ __forceinline__ int read_idx(const int* p) {
    unsigned int u = (unsigned int)*p;
    int ex = (int)((u >> 23) & 0xFF);
    int v;
    if (ex >= 118 && ex <= 140) {
        union { unsigned int i; float f; } c; c.i = u;
        v = (int)(c.f + 0.5f);
    } else {
        v = (int)u;
    }
    return v < 0 ? 0 : (v > 63 ? 63 : v);
}

// ======================= cooperative mega-kernel =======================
__global__ __launch_bounds__(256) void k_mega(
    const float* __restrict__ inp, const float* __restrict__ mem,
    const float* __restrict__ k1,  const float* __restrict__ k2,
    const float* __restrict__ d1,  const float* __restrict__ d2,
    const float* __restrict__ ck,  const float* __restrict__ rec,
    const int* __restrict__ px,    const int* __restrict__ py,
    float* __restrict__ out,       float* __restrict__ ws)
{
    cg::grid_group grid = cg::this_grid();
    __shared__ __align__(16) float SMEM[12544];   // 50.2 KB, phase-unioned
    float* c1p = out + 512;
    const int bid = blockIdx.x;
    const int t = threadIdx.x;

    // ---- Phase A: conv1 partials c1p[chunk][o][4096]; 512 units, 2/block
    {
        float* sm = SMEM;            // [32][104]
        float* sk = SMEM + 3328;     // [9][32][32]
        for (int unit = bid; unit < 512; unit += 256) {
            int tile = unit & 63, chunk = unit >> 6;
            int th = (tile >> 3) * 8, tw = (tile & 7) * 8;
            for (int u = t; u < 800; u += 256) {
                int pix = u >> 3, c4 = u & 7;
                int hh = th - 1 + pix / 10;
                int ww = tw - 1 + pix % 10;
                float4 v = make_float4(0.f, 0.f, 0.f, 0.f);
                if ((unsigned)hh < 64u && (unsigned)ww < 64u)
                    v = *(const float4*)(mem + (size_t)(hh * 64 + ww) * 256
                                             + chunk * 32 + c4 * 4);
                int ib = c4 * 4;
                sm[(ib    ) * 104 + pix] = v.x;
                sm[(ib + 1) * 104 + pix] = v.y;
                sm[(ib + 2) * 104 + pix] = v.z;
                sm[(ib + 3) * 104 + pix] = v.w;
            }
            for (int u = t; u < 2304; u += 256) {
                int tap = u >> 8, r = u & 255;
                const float4* src = (const float4*)(k1 + (size_t)tap * 8192
                                                       + (size_t)chunk * 1024);
                *(float4*)&sk[tap * 1024 + r * 4] = src[r];
            }
            __syncthreads();
            int lh = (t & 63) >> 3, lw = t & 7, og = t >> 6;
            float acc[8];
            #pragma unroll
            for (int j = 0; j < 8; ++j) acc[j] = 0.f;
            for (int dh = 0; dh < 3; ++dh)
                for (int dw = 0; dw < 3; ++dw) {
                    int pixb = (lh + dh) * 10 + (lw + dw);
                    const float* kt = sk + (dh * 3 + dw) * 1024 + og * 8;
                    #pragma unroll 4
                    for (int i = 0; i < 32; ++i) {
                        float m = sm[i * 104 + pixb];
                        float4 ka = *(const float4*)(kt + i * 32);
                        float4 kb = *(const float4*)(kt + i * 32 + 4);
                        acc[0] += m * ka.x; acc[1] += m * ka.y;
                        acc[2] += m * ka.z; acc[3] += m * ka.w;
                        acc[4] += m * kb.x; acc[5] += m * kb.y;
                        acc[6] += m * kb.z; acc[7] += m * kb.w;
                    }
                }
            int p = (th + lh) * 64 + tw + lw;
            float* dst = c1p + (size_t)chunk * 131072
                             + (size_t)(og * 8) * 4096 + p;
            #pragma unroll
            for (int j = 0; j < 8; ++j) dst[(size_t)j * 4096] = acc[j];
            __syncthreads();
        }
    }
    grid.sync();

    // ---- Phase B: conv2 (sums 8 chunk partials during staging); 256 units
    {
        float* sm  = SMEM;           // [32][104]
        float* sk2 = SMEM + 3328;    // [9][32][16]
        int tile = bid & 63, o0 = (bid >> 6) * 16;
        int th = (tile >> 3) * 8, tw = (tile & 7) * 8;
        for (int u = t; u < 3200; u += 256) {
            int i = u / 100, pix = u % 100;
            int hh = th + pix / 10, ww = tw + pix % 10;
            float v = 0.f;
            if (hh < 64 && ww < 64) {
                const float* p = c1p + (size_t)i * 4096 + hh * 64 + ww;
                #pragma unroll
                for (int c = 0; c < 8; ++c) v += p[(size_t)c * 131072];
            }
            sm[i * 104 + pix] = v;
        }
        for (int u = t; u < 1152; u += 256) {
            int tap = u >> 7, r = u & 127;
            int i = r >> 2, o4 = r & 3;
            *(float4*)&sk2[tap * 512 + i * 16 + o4 * 4] =
                *(const float4*)(k2 + (size_t)tap * 2048 + i * 64 + o0 + o4 * 4);
        }
        __syncthreads();
        int pix = t & 63, lh = pix >> 3, lw = pix & 7, og = t >> 6;
        float acc[4] = {0.f, 0.f, 0.f, 0.f};
        for (int dh = 0; dh < 3; ++dh)
            for (int dw = 0; dw < 3; ++dw) {
                int pixb = (lh + dh) * 10 + (lw + dw);
                const float* kt = sk2 + (dh * 3 + dw) * 512 + og * 4;
                #pragma unroll 8
                for (int i = 0; i < 32; ++i) {
                    float m = sm[i * 104 + pixb];
                    float4 kv = *(const float4*)(kt + i * 16);
                    acc[0] += m * kv.x; acc[1] += m * kv.y;
                    acc[2] += m * kv.z; acc[3] += m * kv.w;
                }
            }
        int h = th + lh, w = tw + lw;
        if (h < 62 && w < 62) {
            #pragma unroll
            for (int j = 0; j < 4; ++j)
                ws[W_C2 + (size_t)(o0 + og * 4 + j) * 3844 + h * 62 + w] = acc[j];
        }
        __syncthreads();
    }
    grid.sync();

    // ---- Phase C: r1p (931 units) + transpose (256 units) co-scheduled.
    // c1p is dead; transpose writes new_mem (skips pxy column owned by final).
    {
        for (int w = bid; w < NB_R1 + 256; w += 256) {
            if (w < NB_R1) {
                float* pl   = SMEM;          // 256
                float* sred = SMEM + 256;    // [8][32][4]
                int f0 = w * 256;
                int fmax = FLAT - f0; if (fmax > 256) fmax = 256;
                for (int s = t; s < fmax; s += 256) {
                    int f = f0 + s;
                    int o = f / 3721, r2 = f % 3721;
                    int h = r2 / 61, wq = r2 % 61;
                    const float* b = ws + W_C2 + (size_t)o * 3844 + h * 62 + wq;
                    pl[s] = 0.25f * (b[0] + b[1] + b[62] + b[63]);
                }
                __syncthreads();
                int jq = t & 31, g = t >> 5;
                float4 a = make_float4(0.f, 0.f, 0.f, 0.f);
                for (int s = g; s < fmax; s += 8) {
                    float m = pl[s];
                    float4 dv = *(const float4*)(d1 + (size_t)(f0 + s) * 128 + jq * 4);
                    a.x += m * dv.x; a.y += m * dv.y;
                    a.z += m * dv.z; a.w += m * dv.w;
                }
                *(float4*)&sred[g * 128 + jq * 4] = a;
                __syncthreads();
                if (t < 32) {
                    float4 s4 = make_float4(0.f, 0.f, 0.f, 0.f);
                    #pragma unroll
                    for (int gg = 0; gg < 8; ++gg) {
                        float4 v = *(const float4*)&sred[gg * 128 + t * 4];
                        s4.x += v.x; s4.y += v.y; s4.z += v.z; s4.w += v.w;
                    }
                    *(float4*)(ws + W_P1 + (size_t)w * 128 + t * 4) = s4;
                }
                __syncthreads();
            } else {
                int tu = w - NB_R1;
                float* tile = SMEM;          // [64][65]
                int p0 = (tu & 63) * 64, u0 = (tu >> 6) * 64;
                int x = read_idx(px), y = read_idx(py);
                int pxy = x * 64 + y;
                int lane = t & 63, grp = t >> 6;
                for (int r = 0; r < 16; ++r) {
                    int pr = grp + r * 4;
                    tile[pr * 65 + lane] =
                        mem[(size_t)(p0 + pr) * 256 + u0 + lane];
                }
                __syncthreads();
                for (int r = 0; r < 16; ++r) {
                    int ur = grp + r * 4;
                    if (p0 + lane != pxy)
                        out[512 + (size_t)(u0 + ur) * 4096 + p0 + lane] =
                            tile[lane * 65 + ur];
                }
                __syncthreads();
            }
        }
    }
    grid.sync();

    // ---- Phase D: r1 reduce + r_t / s_t / q_t (block 0; same sum order)
    if (bid == 0) {
        float* s_r1 = SMEM;          // 128
        float* s_in = SMEM + 128;    // 128
        float* s_rt = SMEM + 256;    // 256
        if (t < 128) {
            s_in[t] = inp[t];
            float r = 0.f;
            for (int part = 0; part < 8; ++part) {
                int b0 = part * 117;
                int b1 = b0 + 117; if (b1 > NB_R1) b1 = NB_R1;
                float ps = 0.f;
                for (int b = b0; b < b1; ++b) ps += ws[W_P1 + b * 128 + t];
                r += ps;
            }
            s_r1[t] = r;
        }
        __syncthreads();
        float a2 = 0.f;
        for (int k = 0; k < 128; ++k) a2 += s_r1[k] * d2[k * 256 + t];
        ws[W_RT + t] = a2; s_rt[t] = a2;
        float sv = 0.f;
        for (int k = 0; k < 128; ++k) sv += s_in[k] * rec[k * 256 + t];
        ws[W_ST + t] = sv;
        __syncthreads();
        float q = 0.f;
        for (int k = 0; k < 128; ++k) q += s_in[k] * ck[k * 256 + t];
        for (int k = 0; k < 256; ++k) q += s_rt[k] * ck[(128 + k) * 256 + t];
        ws[W_QT + t] = q;
    }
    grid.sync();

    // ---- Phase E: scores (16 rows/block) + per-block softmax stats
    {
        float* q     = SMEM;         // 256
        float* red16 = SMEM + 256;   // 16
        q[t] = ws[W_QT + t];
        __syncthreads();
        int wave = t >> 6, lane = t & 63;
        int base = bid * 16 + wave * 4;
        float qx = q[lane * 4], qy = q[lane * 4 + 1],
              qz = q[lane * 4 + 2], qw = q[lane * 4 + 3];
        for (int r = 0; r < 4; ++r) {
            int p = base + r;
            float4 m = *(const float4*)(mem + (size_t)p * 256 + lane * 4);
            float acc = m.x * qx + m.y * qy + m.z * qz + m.w * qw;
            for (int off = 32; off; off >>= 1) acc += __shfl_down(acc, off);
            if (lane == 0) red16[wave * 4 + r] = acc;
        }
        __syncthreads();
        if (t < 16) ws[W_SC + bid * 16 + t] = red16[t];
        if (t == 0) {
            float mb = red16[0];
            for (int i = 1; i < 16; ++i) mb = fmaxf(mb, red16[i]);
            float sb = 0.f;
            for (int i = 0; i < 16; ++i) sb += expf(red16[i] - mb);
            ws[W_STAT + bid * 2]     = mb;
            ws[W_STAT + bid * 2 + 1] = sb;
        }
        __syncthreads();
    }
    grid.sync();

    // ---- Phase F: softmax finalize + ctp (64 blocks, 64 rows each)
    if (bid < 64) {
        float* red = SMEM;           // 256
        float* aL  = SMEM + 256;     // 64
        float mv = ws[W_STAT + t * 2];
        float sv = ws[W_STAT + t * 2 + 1];
        red[t] = mv; __syncthreads();
        for (int s = 128; s; s >>= 1) {
            if (t < s) red[t] = fmaxf(red[t], red[t + s]);
            __syncthreads();
        }
        float M = red[0]; __syncthreads();
        red[t] = sv * expf(mv - M); __syncthreads();
        for (int s = 128; s; s >>= 1) {
            if (t < s) red[t] += red[t + s];
            __syncthreads();
        }
        float invS = 1.f / red[0];
        int p0 = bid * 64;
        if (t < 64) aL[t] = expf(ws[W_SC + p0 + t] - M) * invS;
        __syncthreads();
        float acc = 0.f;
        #pragma unroll 8
        for (int pp = 0; pp < 64; ++pp)
            acc += aL[pp] * mem[(size_t)(p0 + pp) * 256 + t];
        ws[W_PC + bid * 256 + t] = acc;
    }
    grid.sync();

    // ---- Phase G: final (block 0)
    if (bid == 0) {
        float* s_diff = SMEM;        // 256
        float* red    = SMEM + 256;  // 256
        int x = read_idx(px), y = read_idx(py);
        int pxy = x * 64 + y;
        float ctv = 0.f;
        #pragma unroll 8
        for (int b = 0; b < 64; ++b) ctv += ws[W_PC + b * 256 + t];
        float stv = ws[W_ST + t], rtv = ws[W_RT + t];
        float memt = mem[(size_t)pxy * 256 + t];
        red[t] = stv * rtv; __syncthreads();
        for (int s = 128; s; s >>= 1) {
            if (t < s) red[t] += red[t + s];
            __syncthreads();
        }
        float gimp = red[0]; __syncthreads();
        red[t] = stv * ctv; __syncthreads();
        for (int s = 128; s; s >>= 1) {
            if (t < s) red[t] += red[t + s];
            __syncthreads();
        }
        float limp = red[0];
        s_diff[t] = memt - stv;
        __syncthreads();
        float d = 0.f;
        for (int k = 0; k < 256; ++k)
            d += s_diff[k] * rec[(128 + k) * 256 + t];
        float frac = limp / (limp + gimp);
        out[t] = ctv;
        out[256 + t] = rtv;
        out[512 + (size_t)t * 4096 + pxy] = memt + frac * d;
    }
}

// ======================= fallback: R17 multi-kernel =======================
#define SOFF_RT   384
#define SOFF_QT   640
#define SOFF_ST   896
#define SOFF_SC   1152
#define SOFF_AT   5248
#define SOFF_PC   9344
#define SOFF_C2B  140416
#define SOFF_P1B  386432

__global__ __launch_bounds__(256) void k_conv1(const float* __restrict__ mem,
                                               const float* __restrict__ k1,
                                               float* __restrict__ c1p) {
    __shared__ float sm[32 * 104];
    __shared__ __align__(16) float sk[9 * 32 * 32];
    int t = threadIdx.x;
    int th = (blockIdx.x >> 3) * 8;
    int tw = (blockIdx.x & 7) * 8;
    int chunk = blockIdx.y;
    for (int u = t; u < 800; u += 256) {
        int pix = u >> 3;
        int c4 = u & 7;
        int hh = th - 1 + pix / 10;
        int ww = tw - 1 + pix % 10;
        float4 v = make_float4(0.f, 0.f, 0.f, 0.f);
        if ((unsigned)hh < 64u && (unsigned)ww < 64u)
            v = *(const float4*)(mem + (size_t)(hh * 64 + ww) * 256
                                     + chunk * 32 + c4 * 4);
        int ib = c4 * 4;
        sm[(ib    ) * 104 + pix] = v.x;
        sm[(ib + 1) * 104 + pix] = v.y;
        sm[(ib + 2) * 104 + pix] = v.z;
        sm[(ib + 3) * 104 + pix] = v.w;
    }
    for (int u = t; u < 2304; u += 256) {
        int tap = u >> 8;
        int r   = u & 255;
        const float4* src = (const float4*)(k1 + (size_t)tap * 8192
                                               + (size_t)chunk * 1024);
        *(float4*)&sk[tap * 1024 + r * 4] = src[r];
    }
    __syncthreads();
    int lh = (t & 63) >> 3, lw = t & 7, og = t >> 6;
    float acc[8];
    #pragma unroll
    for (int j = 0; j < 8; ++j) acc[j] = 0.f;
    for (int dh = 0; dh < 3; ++dh)
        for (int dw = 0; dw < 3; ++dw) {
            int pixb = (lh + dh) * 10 + (lw + dw);
            const float* kt = sk + (dh * 3 + dw) * 1024 + og * 8;
            #pragma unroll 4
            for (int i = 0; i < 32; ++i) {
                float m = sm[i * 104 + pixb];
                float4 ka = *(const float4*)(kt + i * 32);
                float4 kb = *(const float4*)(kt + i * 32 + 4);
                acc[0] += m * ka.x; acc[1] += m * ka.y;
                acc[2] += m * ka.z; acc[3] += m * ka.w;
                acc[4] += m * kb.x; acc[5] += m * kb.y;
                acc[6] += m * kb.z; acc[7] += m * kb.w;
            }
        }
    int p = (th + lh) * 64 + tw + lw;
    float* dst = c1p + (size_t)chunk * 131072 + (size_t)(og * 8) * 4096 + p;
    #pragma unroll
    for (int j = 0; j < 8; ++j)
        dst[(size_t)j * 4096] = acc[j];
}

__global__ __launch_bounds__(256) void k_c1red(float* __restrict__ c1p) {
    int idx = blockIdx.x * 256 + threadIdx.x;
    float s = 0.f;
    #pragma unroll
    for (int c = 0; c < 8; ++c) s += c1p[(size_t)c * 131072 + idx];
    c1p[idx] = s;
}

__global__ __launch_bounds__(256) void k_conv2(const float* __restrict__ c1p,
                                               const float* __restrict__ k2,
                                               float* __restrict__ c2,
                                               int nchunks) {
    __shared__ float sm[32 * 104];
    __shared__ __align__(16) float sk2[9 * 32 * 16];
    int t = threadIdx.x;
    int th = (blockIdx.x >> 3) * 8;
    int tw = (blockIdx.x & 7) * 8;
    int o0 = blockIdx.y * 16;
    for (int u = t; u < 3200; u += 256) {
        int i = u / 100;
        int pix = u % 100;
        int hh = th + pix / 10;
        int ww = tw + pix % 10;
        float v = 0.f;
        if (hh < 64 && ww < 64) {
            const float* p = c1p + (size_t)i * 4096 + hh * 64 + ww;
            for (int c = 0; c < nchunks; ++c)
                v += p[(size_t)c * 131072];
        }
        sm[i * 104 + pix] = v;
    }
    for (int u = t; u < 1152; u += 256) {
        int tap = u >> 7;
        int r = u & 127;
        int i = r >> 2, o4 = r & 3;
        *(float4*)&sk2[tap * 512 + i * 16 + o4 * 4] =
            *(const float4*)(k2 + (size_t)tap * 2048 + i * 64 + o0 + o4 * 4);
    }
    __syncthreads();
    int pix = t & 63;
    int lh = pix >> 3, lw = pix & 7, og = t >> 6;
    float acc[4] = {0.f, 0.f, 0.f, 0.f};
    for (int dh = 0; dh < 3; ++dh)
        for (int dw = 0; dw < 3; ++dw) {
            int pixb = (lh + dh) * 10 + (lw + dw);
            const float* kt = sk2 + (dh * 3 + dw) * 512 + og * 4;
            #pragma unroll 8
            for (int i = 0; i < 32; ++i) {
                float m = sm[i * 104 + pixb];
                float4 kv = *(const float4*)(kt + i * 16);
                acc[0] += m * kv.x; acc[1] += m * kv.y;
                acc[2] += m * kv.z; acc[3] += m * kv.w;
            }
        }
    int h = th + lh, w = tw + lw;
    if (h < 62 && w < 62) {
        #pragma unroll
        for (int j = 0; j < 4; ++j)
            c2[(size_t)(o0 + og * 4 + j) * 3844 + h * 62 + w] = acc[j];
    }
}

__global__ __launch_bounds__(256) void k_r1p(const float* __restrict__ c2,
                                             const float* __restrict__ d1,
                                             float* __restrict__ p1) {
    __shared__ float pl[256];
    __shared__ __align__(16) float sred[8][32][4];
    int t = threadIdx.x;
    int f0 = blockIdx.x * 256;
    int fmax = FLAT - f0; if (fmax > 256) fmax = 256;
    for (int s = t; s < fmax; s += 256) {
        int f = f0 + s;
        int o = f / 3721;
        int r = f % 3721;
        int h = r / 61, w = r % 61;
        const float* b = c2 + (size_t)o * 3844 + h * 62 + w;
        pl[s] = 0.25f * (b[0] + b[1] + b[62] + b[63]);
    }
    __syncthreads();
    int jq = t & 31, g = t >> 5;
    float4 a = make_float4(0.f, 0.f, 0.f, 0.f);
    for (int s = g; s < fmax; s += 8) {
        float m = pl[s];
        float4 dv = *(const float4*)(d1 + (size_t)(f0 + s) * 128 + jq * 4);
        a.x += m * dv.x; a.y += m * dv.y; a.z += m * dv.z; a.w += m * dv.w;
    }
    *(float4*)sred[g][jq] = a;
    __syncthreads();
    if (t < 32) {
        float4 s = make_float4(0.f, 0.f, 0.f, 0.f);
        #pragma unroll
        for (int gg = 0; gg < 8; ++gg) {
            float4 v = *(const float4*)sred[gg][t];
            s.x += v.x; s.y += v.y; s.z += v.z; s.w += v.w;
        }
        *(float4*)(p1 + (size_t)blockIdx.x * 128 + t * 4) = s;
    }
}

__global__ __launch_bounds__(1024) void k_fused(const float* __restrict__ p1,
                                                const float* __restrict__ d2,
                                                const float* __restrict__ inp,
                                                const float* __restrict__ ck,
                                                const float* __restrict__ rec,
                                                float* __restrict__ rt,
                                                float* __restrict__ qt,
                                                float* __restrict__ st) {
    __shared__ float p2s[8][128];
    __shared__ float s_r1[128], s_in[128], s_rt[256];
    int t = threadIdx.x;
    int j = t & 127, part = t >> 7;
    int b0 = part * 117;
    int b1 = b0 + 117; if (b1 > NB_R1) b1 = NB_R1;
    float s = 0.f;
    for (int b = b0; b < b1; ++b) s += p1[b * 128 + j];
    p2s[part][j] = s;
    if (t < 128) s_in[t] = inp[t];
    __syncthreads();
    if (t < 128) {
        float r = 0.f;
        #pragma unroll
        for (int c = 0; c < 8; ++c) r += p2s[c][t];
        s_r1[t] = r;
    }
    __syncthreads();
    if (t < 256) {
        float a = 0.f;
        for (int k = 0; k < 128; ++k) a += s_r1[k] * d2[k * 256 + t];
        rt[t] = a; s_rt[t] = a;
        float sv = 0.f;
        for (int k = 0; k < 128; ++k) sv += s_in[k] * rec[k * 256 + t];
        st[t] = sv;
    }
    __syncthreads();
    if (t < 256) {
        float q = 0.f;
        for (int k = 0; k < 128; ++k) q += s_in[k] * ck[k * 256 + t];
        for (int k = 0; k < 256; ++k) q += s_rt[k] * ck[(128 + k) * 256 + t];
        qt[t] = q;
    }
}

__global__ __launch_bounds__(256) void k_scores(const float* __restrict__ qt,
                                                const float* __restrict__ mem,
                                                float* __restrict__ scores) {
    __shared__ float q[256];
    int t = threadIdx.x;
    q[t] = qt[t];
    __syncthreads();
    int wave = t >> 6, lane = t & 63;
    int base = blockIdx.x * 16 + wave * 4;
    float qx = q[lane * 4], qy = q[lane * 4 + 1],
          qz = q[lane * 4 + 2], qw = q[lane * 4 + 3];
    for (int r = 0; r < 4; ++r) {
        int p = base + r;
        float4 m = *(const float4*)(mem + (size_t)p * 256 + lane * 4);
        float acc = m.x * qx + m.y * qy + m.z * qz + m.w * qw;
        for (int off = 32; off; off >>= 1) acc += __shfl_down(acc, off);
        if (lane == 0) scores[p] = acc;
    }
}

__global__ __launch_bounds__(256) void k_softmax(const float* __restrict__ scores,
                                                 float* __restrict__ at) {
    __shared__ float red[256];
    int t = threadIdx.x;
    float m = -1e30f;
    for (int i = t; i < 4096; i += 256) m = fmaxf(m, scores[i]);
    red[t] = m; __syncthreads();
    for (int s = 128; s; s >>= 1) { if (t < s) red[t] = fmaxf(red[t], red[t + s]); __syncthreads(); }
    float mx = red[0]; __syncthreads();
    float sum = 0.f;
    for (int i = t; i < 4096; i += 256) sum += expf(scores[i] - mx);
    red[t] = sum; __syncthreads();
    for (int s = 128; s; s >>= 1) { if (t < s) red[t] += red[t + s]; __syncthreads(); }
    float inv = 1.f / red[0];
    for (int i = t; i < 4096; i += 256) at[i] = expf(scores[i] - mx) * inv;
}

__global__ __launch_bounds__(256) void k_ctp(const float* __restrict__ at,
                                             const float* __restrict__ mem,
                                             float* __restrict__ pc) {
    __shared__ float a[64];
    int t = threadIdx.x;
    int p0 = blockIdx.x * 64;
    if (t < 64) a[t] = at[p0 + t];
    __syncthreads();
    float acc = 0.f;
    #pragma unroll 8
    for (int pp = 0; pp < 64; ++pp)
        acc += a[pp] * mem[(size_t)(p0 + pp) * 256 + t];
    pc[blockIdx.x * 256 + t] = acc;
}

__global__ __launch_bounds__(256) void k_final(const float* __restrict__ rt,
                                               const float* __restrict__ st,
                                               const float* __restrict__ pc,
                                               const float* __restrict__ mem,
                                               const float* __restrict__ rec,
                                               const int* __restrict__ px,
                                               const int* __restrict__ py,
                                               float* __restrict__ out) {
    __shared__ float s_diff[256], red[256];
    int t = threadIdx.x;
    int x = read_idx(px), y = read_idx(py);
    int pxy = x * 64 + y;
    float ctv = 0.f;
    #pragma unroll 8
    for (int b = 0; b < 64; ++b) ctv += pc[b * 256 + t];
    float stv = st[t], rtv = rt[t];
    float memt = mem[(size_t)pxy * 256 + t];
    red[t] = stv * rtv; __syncthreads();
    for (int s = 128; s; s >>= 1) { if (t < s) red[t] += red[t + s]; __syncthreads(); }
    float gimp = red[0]; __syncthreads();
    red[t] = stv * ctv; __syncthreads();
    for (int s = 128; s; s >>= 1) { if (t < s) red[t] += red[t + s]; __syncthreads(); }
    float limp = red[0];
    s_diff[t] = memt - stv;
    __syncthreads();
    float d = 0.f;
    for (int k = 0; k < 256; ++k)
        d += s_diff[k] * rec[(128 + k) * 256 + t];
    float frac = limp / (limp + gimp);
    float nv = memt + frac * d;
    out[t] = ctv;
    out[256 + t] = rtv;
    out[512 + (size_t)t * 4096 + pxy] = nv;
}

__global__ __launch_bounds__(256) void k_transpose(const float* __restrict__ mem,
                                                   const int* __restrict__ px,
                                                   const int* __restrict__ py,
                                                   float* __restrict__ outm) {
    __shared__ float tile[64][65];
    int t = threadIdx.x;
    int p0 = blockIdx.x * 64;
    int u0 = blockIdx.y * 64;
    int x = read_idx(px), y = read_idx(py);
    int pxy = x * 64 + y;
    int lane = t & 63, grp = t >> 6;
    for (int r = 0; r < 16; ++r) {
        int pr = grp + r * 4;
        tile[pr][lane] = mem[(size_t)(p0 + pr) * 256 + u0 + lane];
    }
    __syncthreads();
    for (int r = 0; r < 16; ++r) {
        int ur = grp + r * 4;
        if (p0 + lane != pxy)
            outm[(size_t)(u0 + ur) * 4096 + p0 + lane] = tile[lane][ur];
    }
}

extern "C" void kernel_launch(void* const* d_in, const int* in_sizes, int n_in,
                              void* d_out, int out_size, void* d_ws, size_t ws_size,
                              hipStream_t stream) {
    const float* inp = (const float*)d_in[0];
    const float* mem = (const float*)d_in[1];
    const float* k1  = (const float*)d_in[2];
    const float* k2  = (const float*)d_in[3];
    const float* d1  = (const float*)d_in[4];
    const float* d2  = (const float*)d_in[5];
    const float* ck  = (const float*)d_in[6];
    const float* rec = (const float*)d_in[7];
    const int* px = (const int*)d_in[8];
    const int* py = (const int*)d_in[9];
    float* out = (float*)d_out;
    float* scr = out + 512;
    float* wsf = (float*)d_ws;

    if (wsf != nullptr && ws_size >= (size_t)W_END * sizeof(float)) {
        void* args[] = {(void*)&inp, (void*)&mem, (void*)&k1, (void*)&k2,
                        (void*)&d1,  (void*)&d2,  (void*)&ck, (void*)&rec,
                        (void*)&px,  (void*)&py,  (void*)&out, (void*)&wsf};
        hipError_t e = hipLaunchCooperativeKernel(
            reinterpret_cast<const void*>(&k_mega),
            dim3(256), dim3(256), args, 0, stream);
        if (e == hipSuccess) return;
    }

    // -------- fallback: R17 multi-kernel path (scr-only layout) --------
    float* C2 = scr + SOFF_C2B;
    float* P1 = scr + SOFF_P1B;
    k_conv1<<<dim3(64, 8), 256, 0, stream>>>(mem, k1, scr);
    k_c1red<<<512, 256, 0, stream>>>(scr);
    k_conv2<<<dim3(64, 4), 256, 0, stream>>>(scr, k2, C2, 1);
    k_r1p<<<NB_R1, 256, 0, stream>>>(C2, d1, P1);
    k_fused<<<1, 1024, 0, stream>>>(P1, d2, inp, ck, rec,
                                    scr + SOFF_RT, scr + SOFF_QT, scr + SOFF_ST);
    k_scores<<<256, 256, 0, stream>>>(scr + SOFF_QT, mem, scr + SOFF_SC);
    k_softmax<<<1, 256, 0, stream>>>(scr + SOFF_SC, scr + SOFF_AT);
    k_ctp<<<64, 256, 0, stream>>>(scr + SOFF_AT, mem, scr + SOFF_PC);
    k_final<<<1, 256, 0, stream>>>(scr + SOFF_RT, scr + SOFF_ST, scr + SOFF_PC,
                                   mem, rec, px, py, out);
    k_transpose<<<dim3(64, 4), 256, 0, stream>>>(mem, px, py, out + 512);
}

// Round 5
// 364.894 us; speedup vs baseline: 1.4808x; 1.4808x over previous
//
#include <hip/hip_runtime.h>

// NeuralMapCell — ROUND 20. R19 resubmit minus the atomic-ticket pattern
// (suspected container-killer / graph-capture tripwire). 6 launches (ws):
//   K1 conv1 (512 blk, LDS stage stride 105 bank fix)
//   K2 conv2 (256 blk, sums 8 chunk partials during staging)
//   K3 r1p + transpose co-kernel (1187 blk, block-range split)
//   K4 scores-fused (64 blk x 512 thr): every block redundantly computes
//      r1 (exact 8x117 order) + rt/st/qt; writes its 64 score rows + stats
//   K5 softmax-finalize + ctp partials (64 blk)
//   K6 final (1 blk, ct-reduce folded)
// Fallback (no ws): + c1red, transpose runs last. No atomics anywhere.
//
// d_out = float[1049088]: c_t[256] r_t[256] new_mem[1048576].
// scr = out + 512; c1p[8][32][4096] fills scr, dead after K2 (ws path), so
// K3's transpose overwrites scr with the real new_mem (skips pxy column).
#define FLAT  238144      // 64*61*61
#define NB_R1 931

// ws float offsets (ws path)
#define W_C2   0          // 246016
#define W_P1   246016     // 119168 -> 365184
#define W_RT   365184     // 256
#define W_ST   365440     // 256
#define W_SC   365696     // 4096
#define W_STAT 369792     // 128 (64 x {max,expsum})
#define W_PC   369920     // 16384 (64 x 256)
#define W_END  386304

// scr float offsets (fallback path; transpose runs LAST, separately)
#define F_C2   140416
#define F_P1   386432     // -> 505600
#define F_RT   505600
#define F_ST   505856
#define F_SC   506112
#define F_STAT 510208
#define F_PC   510336     // -> 526720

__device__ __forceinline__ int read_idx(const int* p) {
    unsigned int u = (unsigned int)*p;
    int ex = (int)((u >> 23) & 0xFF);
    int v;
    if (ex >= 118 && ex <= 140) {
        union { unsigned int i; float f; } c; c.i = u;
        v = (int)(c.f + 0.5f);
    } else {
        v = (int)u;
    }
    return v < 0 ? 0 : (v > 63 ? 63 : v);
}

// ---- K1: conv1 (cross-corr, SAME, 3x3, 256->32): c1p[chunk][o][4096]
__global__ __launch_bounds__(256) void k_conv1(const float* __restrict__ mem,
                                               const float* __restrict__ k1,
                                               float* __restrict__ c1p) {
    __shared__ float sm[32 * 105];          // stride 105: staging banks spread
    __shared__ __align__(16) float sk[9 * 32 * 32];
    int t = threadIdx.x;
    int th = (blockIdx.x >> 3) * 8;
    int tw = (blockIdx.x & 7) * 8;
    int chunk = blockIdx.y;
    for (int u = t; u < 800; u += 256) {
        int pix = u >> 3;
        int c4 = u & 7;
        int hh = th - 1 + pix / 10;
        int ww = tw - 1 + pix % 10;
        float4 v = make_float4(0.f, 0.f, 0.f, 0.f);
        if ((unsigned)hh < 64u && (unsigned)ww < 64u)
            v = *(const float4*)(mem + (size_t)(hh * 64 + ww) * 256
                                     + chunk * 32 + c4 * 4);
        int ib = c4 * 4;
        sm[(ib    ) * 105 + pix] = v.x;
        sm[(ib + 1) * 105 + pix] = v.y;
        sm[(ib + 2) * 105 + pix] = v.z;
        sm[(ib + 3) * 105 + pix] = v.w;
    }
    for (int u = t; u < 2304; u += 256) {
        int tap = u >> 8;
        int r   = u & 255;
        const float4* src = (const float4*)(k1 + (size_t)tap * 8192
                                               + (size_t)chunk * 1024);
        *(float4*)&sk[tap * 1024 + r * 4] = src[r];
    }
    __syncthreads();
    int lh = (t & 63) >> 3, lw = t & 7, og = t >> 6;
    float acc[8];
    #pragma unroll
    for (int j = 0; j < 8; ++j) acc[j] = 0.f;
    for (int dh = 0; dh < 3; ++dh)
        for (int dw = 0; dw < 3; ++dw) {
            int pixb = (lh + dh) * 10 + (lw + dw);
            const float* kt = sk + (dh * 3 + dw) * 1024 + og * 8;
            #pragma unroll 4
            for (int i = 0; i < 32; ++i) {
                float m = sm[i * 105 + pixb];
                float4 ka = *(const float4*)(kt + i * 32);
                float4 kb = *(const float4*)(kt + i * 32 + 4);
                acc[0] += m * ka.x; acc[1] += m * ka.y;
                acc[2] += m * ka.z; acc[3] += m * ka.w;
                acc[4] += m * kb.x; acc[5] += m * kb.y;
                acc[6] += m * kb.z; acc[7] += m * kb.w;
            }
        }
    int p = (th + lh) * 64 + tw + lw;
    float* dst = c1p + (size_t)chunk * 131072 + (size_t)(og * 8) * 4096 + p;
    #pragma unroll
    for (int j = 0; j < 8; ++j)
        dst[(size_t)j * 4096] = acc[j];
}

// ---- fallback only: compact 8 chunk partials (ascending order)
__global__ __launch_bounds__(256) void k_c1red(float* __restrict__ c1p) {
    int idx = blockIdx.x * 256 + threadIdx.x;
    float s = 0.f;
    #pragma unroll
    for (int c = 0; c < 8; ++c) s += c1p[(size_t)c * 131072 + idx];
    c1p[idx] = s;
}

// ---- K2: conv2 (VALID, 3x3, 32->64); staging sums nchunks partials
__global__ __launch_bounds__(256) void k_conv2(const float* __restrict__ c1p,
                                               const float* __restrict__ k2,
                                               float* __restrict__ c2,
                                               int nchunks) {
    __shared__ float sm[32 * 104];
    __shared__ __align__(16) float sk2[9 * 32 * 16];
    int t = threadIdx.x;
    int th = (blockIdx.x >> 3) * 8;
    int tw = (blockIdx.x & 7) * 8;
    int o0 = blockIdx.y * 16;
    for (int u = t; u < 3200; u += 256) {
        int i = u / 100;
        int pix = u % 100;
        int hh = th + pix / 10;
        int ww = tw + pix % 10;
        float v = 0.f;
        if (hh < 64 && ww < 64) {
            const float* p = c1p + (size_t)i * 4096 + hh * 64 + ww;
            for (int c = 0; c < nchunks; ++c)
                v += p[(size_t)c * 131072];
        }
        sm[i * 104 + pix] = v;
    }
    for (int u = t; u < 1152; u += 256) {
        int tap = u >> 7;
        int r = u & 127;
        int i = r >> 2, o4 = r & 3;
        *(float4*)&sk2[tap * 512 + i * 16 + o4 * 4] =
            *(const float4*)(k2 + (size_t)tap * 2048 + i * 64 + o0 + o4 * 4);
    }
    __syncthreads();
    int pix = t & 63;
    int lh = pix >> 3, lw = pix & 7, og = t >> 6;
    float acc[4] = {0.f, 0.f, 0.f, 0.f};
    for (int dh = 0; dh < 3; ++dh)
        for (int dw = 0; dw < 3; ++dw) {
            int pixb = (lh + dh) * 10 + (lw + dw);
            const float* kt = sk2 + (dh * 3 + dw) * 512 + og * 4;
            #pragma unroll 8
            for (int i = 0; i < 32; ++i) {
                float m = sm[i * 104 + pixb];
                float4 kv = *(const float4*)(kt + i * 16);
                acc[0] += m * kv.x; acc[1] += m * kv.y;
                acc[2] += m * kv.z; acc[3] += m * kv.w;
            }
        }
    int h = th + lh, w = tw + lw;
    if (h < 62 && w < 62) {
        #pragma unroll
        for (int j = 0; j < 4; ++j)
            c2[(size_t)(o0 + og * 4 + j) * 3844 + h * 62 + w] = acc[j];
    }
}

// ---- K3: r1p (blocks 0..930) + transpose (blocks 931..1186)
__global__ __launch_bounds__(256) void k_r1pt(const float* __restrict__ c2,
                                              const float* __restrict__ d1,
                                              float* __restrict__ p1,
                                              const float* __restrict__ mem,
                                              const int* __restrict__ px,
                                              const int* __restrict__ py,
                                              float* __restrict__ outm) {
    __shared__ __align__(16) float SM[4160];
    int t = threadIdx.x;
    int bid = blockIdx.x;
    if (bid < NB_R1) {
        float* pl   = SM;            // 256
        float* sred = SM + 256;      // [8][32][4]
        int f0 = bid * 256;
        int fmax = FLAT - f0; if (fmax > 256) fmax = 256;
        for (int s = t; s < fmax; s += 256) {
            int f = f0 + s;
            int o = f / 3721;
            int r = f % 3721;
            int h = r / 61, w = r % 61;
            const float* b = c2 + (size_t)o * 3844 + h * 62 + w;
            pl[s] = 0.25f * (b[0] + b[1] + b[62] + b[63]);
        }
        __syncthreads();
        int jq = t & 31, g = t >> 5;
        float4 a = make_float4(0.f, 0.f, 0.f, 0.f);
        for (int s = g; s < fmax; s += 8) {
            float m = pl[s];
            float4 dv = *(const float4*)(d1 + (size_t)(f0 + s) * 128 + jq * 4);
            a.x += m * dv.x; a.y += m * dv.y; a.z += m * dv.z; a.w += m * dv.w;
        }
        *(float4*)&sred[(g * 32 + jq) * 4] = a;
        __syncthreads();
        if (t < 32) {
            float4 s4 = make_float4(0.f, 0.f, 0.f, 0.f);
            #pragma unroll
            for (int gg = 0; gg < 8; ++gg) {
                float4 v = *(const float4*)&sred[(gg * 32 + t) * 4];
                s4.x += v.x; s4.y += v.y; s4.z += v.z; s4.w += v.w;
            }
            *(float4*)(p1 + (size_t)bid * 128 + t * 4) = s4;
        }
    } else {
        int tu = bid - NB_R1;
        float* tile = SM;            // [64][65]
        int p0 = (tu & 63) * 64;
        int u0 = (tu >> 6) * 64;
        int x = read_idx(px), y = read_idx(py);
        int pxy = x * 64 + y;
        int lane = t & 63, grp = t >> 6;
        for (int r = 0; r < 16; ++r) {
            int pr = grp + r * 4;
            tile[pr * 65 + lane] = mem[(size_t)(p0 + pr) * 256 + u0 + lane];
        }
        __syncthreads();
        for (int r = 0; r < 16; ++r) {
            int ur = grp + r * 4;
            if (p0 + lane != pxy)
                outm[(size_t)(u0 + ur) * 4096 + p0 + lane] = tile[lane * 65 + ur];
        }
    }
}

// ---- K4: scores-fused. 64 blocks x 512 thr. Every block computes r1
// (exact 8x117 part order) + rt/st/qt, then its 64 score rows + stats.
__global__ __launch_bounds__(512) void k_sf(const float* __restrict__ p1,
                                            const float* __restrict__ d2,
                                            const float* __restrict__ inp,
                                            const float* __restrict__ ck,
                                            const float* __restrict__ rec,
                                            const float* __restrict__ mem,
                                            float* __restrict__ rt,
                                            float* __restrict__ st,
                                            float* __restrict__ sc,
                                            float* __restrict__ stat) {
    __shared__ float p2s[8][128];
    __shared__ float s_r1[128], s_in[128], s_rt[256], s_q[256];
    __shared__ float rowv[64];
    int t = threadIdx.x;
    int bid = blockIdx.x;
    int j = t & 127, part = t >> 7;          // part 0..3 -> handles part, part+4
    {
        int b0 = part * 117, b1 = b0 + 117; if (b1 > NB_R1) b1 = NB_R1;
        float s0 = 0.f;
        for (int b = b0; b < b1; ++b) s0 += p1[b * 128 + j];
        int c0 = (part + 4) * 117, c1 = c0 + 117; if (c1 > NB_R1) c1 = NB_R1;
        float s1 = 0.f;
        for (int b = c0; b < c1; ++b) s1 += p1[b * 128 + j];
        p2s[part][j] = s0;
        p2s[part + 4][j] = s1;
    }
    if (t < 128) s_in[t] = inp[t];
    __syncthreads();
    if (t < 128) {
        float r = 0.f;
        #pragma unroll
        for (int c = 0; c < 8; ++c) r += p2s[c][t];
        s_r1[t] = r;
    }
    __syncthreads();
    if (t < 256) {
        float a = 0.f;
        for (int k = 0; k < 128; ++k) a += s_r1[k] * d2[k * 256 + t];
        s_rt[t] = a;
        float sv = 0.f;
        for (int k = 0; k < 128; ++k) sv += s_in[k] * rec[k * 256 + t];
        if (bid == 0) { rt[t] = a; st[t] = sv; }
    }
    __syncthreads();
    if (t < 256) {
        float q = 0.f;
        for (int k = 0; k < 128; ++k) q += s_in[k] * ck[k * 256 + t];
        for (int k = 0; k < 256; ++k) q += s_rt[k] * ck[(128 + k) * 256 + t];
        s_q[t] = q;
    }
    __syncthreads();
    int wave = t >> 6, lane = t & 63;
    float qx = s_q[lane * 4], qy = s_q[lane * 4 + 1],
          qz = s_q[lane * 4 + 2], qw = s_q[lane * 4 + 3];
    for (int r = 0; r < 8; ++r) {
        int p = bid * 64 + wave * 8 + r;
        float4 m = *(const float4*)(mem + (size_t)p * 256 + lane * 4);
        float acc = m.x * qx + m.y * qy + m.z * qz + m.w * qw;
        for (int off = 32; off; off >>= 1) acc += __shfl_down(acc, off);
        if (lane == 0) rowv[wave * 8 + r] = acc;
    }
    __syncthreads();
    if (t < 64) sc[bid * 64 + t] = rowv[t];
    if (t == 0) {
        float mb = rowv[0];
        for (int i = 1; i < 64; ++i) mb = fmaxf(mb, rowv[i]);
        float sb = 0.f;
        for (int i = 0; i < 64; ++i) sb += expf(rowv[i] - mb);
        stat[bid * 2]     = mb;
        stat[bid * 2 + 1] = sb;
    }
}

// ---- K5: softmax finalize + ctp partials (64 blocks, 64 rows each)
__global__ __launch_bounds__(256) void k_ctp(const float* __restrict__ stat,
                                             const float* __restrict__ sc,
                                             const float* __restrict__ mem,
                                             float* __restrict__ pc) {
    __shared__ float sm_[64], ss_[64], aux[2], aL[64];
    int t = threadIdx.x;
    int bid = blockIdx.x;
    if (t < 64) { sm_[t] = stat[t * 2]; ss_[t] = stat[t * 2 + 1]; }
    __syncthreads();
    if (t == 0) {
        float M = sm_[0];
        for (int i = 1; i < 64; ++i) M = fmaxf(M, sm_[i]);
        float S = 0.f;
        for (int i = 0; i < 64; ++i) S += ss_[i] * expf(sm_[i] - M);
        aux[0] = M; aux[1] = 1.f / S;
    }
    __syncthreads();
    float M = aux[0], invS = aux[1];
    int p0 = bid * 64;
    if (t < 64) aL[t] = expf(sc[p0 + t] - M) * invS;
    __syncthreads();
    float acc = 0.f;
    #pragma unroll 8
    for (int pp = 0; pp < 64; ++pp)
        acc += aL[pp] * mem[(size_t)(p0 + pp) * 256 + t];
    pc[bid * 256 + t] = acc;
}

// ---- K6: final (1 block; ct reduce folded, ascending block order)
__global__ __launch_bounds__(256) void k_final(const float* __restrict__ rt,
                                               const float* __restrict__ st,
                                               const float* __restrict__ pc,
                                               const float* __restrict__ mem,
                                               const float* __restrict__ rec,
                                               const int* __restrict__ px,
                                               const int* __restrict__ py,
                                               float* __restrict__ out) {
    __shared__ float s_diff[256], red[256];
    int t = threadIdx.x;
    int x = read_idx(px), y = read_idx(py);
    int pxy = x * 64 + y;
    float ctv = 0.f;
    #pragma unroll 8
    for (int b = 0; b < 64; ++b) ctv += pc[b * 256 + t];
    float stv = st[t], rtv = rt[t];
    float memt = mem[(size_t)pxy * 256 + t];
    red[t] = stv * rtv; __syncthreads();
    for (int s = 128; s; s >>= 1) { if (t < s) red[t] += red[t + s]; __syncthreads(); }
    float gimp = red[0]; __syncthreads();
    red[t] = stv * ctv; __syncthreads();
    for (int s = 128; s; s >>= 1) { if (t < s) red[t] += red[t + s]; __syncthreads(); }
    float limp = red[0];
    s_diff[t] = memt - stv;
    __syncthreads();
    float d = 0.f;
    for (int k = 0; k < 256; ++k)
        d += s_diff[k] * rec[(128 + k) * 256 + t];
    float frac = limp / (limp + gimp);
    out[t] = ctv;
    out[256 + t] = rtv;
    out[512 + (size_t)t * 4096 + pxy] = memt + frac * d;
}

// ---- fallback only: standalone transpose (runs LAST on scr path)
__global__ __launch_bounds__(256) void k_transpose(const float* __restrict__ mem,
                                                   const int* __restrict__ px,
                                                   const int* __restrict__ py,
                                                   float* __restrict__ outm) {
    __shared__ float tile[64][65];
    int t = threadIdx.x;
    int p0 = blockIdx.x * 64;
    int u0 = blockIdx.y * 64;
    int x = read_idx(px), y = read_idx(py);
    int pxy = x * 64 + y;
    int lane = t & 63, grp = t >> 6;
    for (int r = 0; r < 16; ++r) {
        int pr = grp + r * 4;
        tile[pr][lane] = mem[(size_t)(p0 + pr) * 256 + u0 + lane];
    }
    __syncthreads();
    for (int r = 0; r < 16; ++r) {
        int ur = grp + r * 4;
        if (p0 + lane != pxy)
            outm[(size_t)(u0 + ur) * 4096 + p0 + lane] = tile[lane][ur];
    }
}

extern "C" void kernel_launch(void* const* d_in, const int* in_sizes, int n_in,
                              void* d_out, int out_size, void* d_ws, size_t ws_size,
                              hipStream_t stream) {
    const float* inp = (const float*)d_in[0];
    const float* mem = (const float*)d_in[1];
    const float* k1  = (const float*)d_in[2];
    const float* k2  = (const float*)d_in[3];
    const float* d1  = (const float*)d_in[4];
    const float* d2  = (const float*)d_in[5];
    const float* ck  = (const float*)d_in[6];
    const float* rec = (const float*)d_in[7];
    const int* px = (const int*)d_in[8];
    const int* py = (const int*)d_in[9];
    float* out = (float*)d_out;
    float* scr = out + 512;
    float* ws  = (float*)d_ws;

    bool useWs = (ws != nullptr) && (ws_size >= (size_t)W_END * sizeof(float));

    if (useWs) {
        k_conv1<<<dim3(64, 8), 256, 0, stream>>>(mem, k1, scr);
        k_conv2<<<dim3(64, 4), 256, 0, stream>>>(scr, k2, ws + W_C2, 8);
        k_r1pt<<<NB_R1 + 256, 256, 0, stream>>>(ws + W_C2, d1, ws + W_P1,
                                                mem, px, py, scr);
        k_sf<<<64, 512, 0, stream>>>(ws + W_P1, d2, inp, ck, rec, mem,
                                     ws + W_RT, ws + W_ST, ws + W_SC,
                                     ws + W_STAT);
        k_ctp<<<64, 256, 0, stream>>>(ws + W_STAT, ws + W_SC, mem, ws + W_PC);
        k_final<<<1, 256, 0, stream>>>(ws + W_RT, ws + W_ST, ws + W_PC,
                                       mem, rec, px, py, out);
    } else {
        k_conv1<<<dim3(64, 8), 256, 0, stream>>>(mem, k1, scr);
        k_c1red<<<512, 256, 0, stream>>>(scr);
        k_conv2<<<dim3(64, 4), 256, 0, stream>>>(scr, k2, scr + F_C2, 1);
        k_r1pt<<<NB_R1, 256, 0, stream>>>(scr + F_C2, d1, scr + F_P1,
                                          mem, px, py, scr);
        k_sf<<<64, 512, 0, stream>>>(scr + F_P1, d2, inp, ck, rec, mem,
                                     scr + F_RT, scr + F_ST, scr + F_SC,
                                     scr + F_STAT);
        k_ctp<<<64, 256, 0, stream>>>(scr + F_STAT, scr + F_SC, mem,
                                      scr + F_PC);
        k_final<<<1, 256, 0, stream>>>(scr + F_RT, scr + F_ST, scr + F_PC,
                                       mem, rec, px, py, out);
        k_transpose<<<dim3(64, 4), 256, 0, stream>>>(mem, px, py, out + 512);
    }
}

// Round 6
// 348.875 us; speedup vs baseline: 1.5488x; 1.0459x over previous
//
#include <hip/hip_runtime.h>

// NeuralMapCell — ROUND 21. R20 profile: k_sf = 92us (top dispatch!) — the
// redundant per-block r1/rt/qt compute was latency-poison (VALU 1.6%, VGPR
// 36, occ 5.5%). Fix: split back into 1-block k_fused (exact R16 numerics,
// runs ONCE) + 64-block k_scores emitting per-block softmax stats (same
// stat math as R20 -> K5/K6 unchanged). 7 launches (ws path). Launch-gap
// theory demoted: gaps ~5us, kernel interiors dominate.
//
// d_out = float[1049088]: c_t[256] r_t[256] new_mem[1048576].
// scr = out + 512; c1p[8][32][4096] fills scr, dead after K2 (ws path), so
// K3's transpose overwrites scr with the real new_mem (skips pxy column).
#define FLAT  238144      // 64*61*61
#define NB_R1 931

// ws float offsets (ws path)
#define W_C2   0          // 246016
#define W_P1   246016     // 119168 -> 365184
#define W_RT   365184     // 256
#define W_ST   365440     // 256
#define W_QT   365696     // 256
#define W_SC   365952     // 4096
#define W_STAT 370048     // 128 (64 x {max,expsum})
#define W_PC   370176     // 16384 (64 x 256)
#define W_END  386560

// scr float offsets (fallback path; transpose runs LAST, separately)
#define F_C2   140416
#define F_P1   386432     // -> 505600
#define F_RT   505600
#define F_ST   505856
#define F_QT   506112
#define F_SC   506368
#define F_STAT 510464
#define F_PC   510592     // -> 526976

__device__ __forceinline__ int read_idx(const int* p) {
    unsigned int u = (unsigned int)*p;
    int ex = (int)((u >> 23) & 0xFF);
    int v;
    if (ex >= 118 && ex <= 140) {
        union { unsigned int i; float f; } c; c.i = u;
        v = (int)(c.f + 0.5f);
    } else {
        v = (int)u;
    }
    return v < 0 ? 0 : (v > 63 ? 63 : v);
}

// ---- K1: conv1 (cross-corr, SAME, 3x3, 256->32): c1p[chunk][o][4096]
__global__ __launch_bounds__(256) void k_conv1(const float* __restrict__ mem,
                                               const float* __restrict__ k1,
                                               float* __restrict__ c1p) {
    __shared__ float sm[32 * 105];          // stride 105: staging banks spread
    __shared__ __align__(16) float sk[9 * 32 * 32];
    int t = threadIdx.x;
    int th = (blockIdx.x >> 3) * 8;
    int tw = (blockIdx.x & 7) * 8;
    int chunk = blockIdx.y;
    for (int u = t; u < 800; u += 256) {
        int pix = u >> 3;
        int c4 = u & 7;
        int hh = th - 1 + pix / 10;
        int ww = tw - 1 + pix % 10;
        float4 v = make_float4(0.f, 0.f, 0.f, 0.f);
        if ((unsigned)hh < 64u && (unsigned)ww < 64u)
            v = *(const float4*)(mem + (size_t)(hh * 64 + ww) * 256
                                     + chunk * 32 + c4 * 4);
        int ib = c4 * 4;
        sm[(ib    ) * 105 + pix] = v.x;
        sm[(ib + 1) * 105 + pix] = v.y;
        sm[(ib + 2) * 105 + pix] = v.z;
        sm[(ib + 3) * 105 + pix] = v.w;
    }
    for (int u = t; u < 2304; u += 256) {
        int tap = u >> 8;
        int r   = u & 255;
        const float4* src = (const float4*)(k1 + (size_t)tap * 8192
                                               + (size_t)chunk * 1024);
        *(float4*)&sk[tap * 1024 + r * 4] = src[r];
    }
    __syncthreads();
    int lh = (t & 63) >> 3, lw = t & 7, og = t >> 6;
    float acc[8];
    #pragma unroll
    for (int j = 0; j < 8; ++j) acc[j] = 0.f;
    for (int dh = 0; dh < 3; ++dh)
        for (int dw = 0; dw < 3; ++dw) {
            int pixb = (lh + dh) * 10 + (lw + dw);
            const float* kt = sk + (dh * 3 + dw) * 1024 + og * 8;
            #pragma unroll 4
            for (int i = 0; i < 32; ++i) {
                float m = sm[i * 105 + pixb];
                float4 ka = *(const float4*)(kt + i * 32);
                float4 kb = *(const float4*)(kt + i * 32 + 4);
                acc[0] += m * ka.x; acc[1] += m * ka.y;
                acc[2] += m * ka.z; acc[3] += m * ka.w;
                acc[4] += m * kb.x; acc[5] += m * kb.y;
                acc[6] += m * kb.z; acc[7] += m * kb.w;
            }
        }
    int p = (th + lh) * 64 + tw + lw;
    float* dst = c1p + (size_t)chunk * 131072 + (size_t)(og * 8) * 4096 + p;
    #pragma unroll
    for (int j = 0; j < 8; ++j)
        dst[(size_t)j * 4096] = acc[j];
}

// ---- fallback only: compact 8 chunk partials (ascending order)
__global__ __launch_bounds__(256) void k_c1red(float* __restrict__ c1p) {
    int idx = blockIdx.x * 256 + threadIdx.x;
    float s = 0.f;
    #pragma unroll
    for (int c = 0; c < 8; ++c) s += c1p[(size_t)c * 131072 + idx];
    c1p[idx] = s;
}

// ---- K2: conv2 (VALID, 3x3, 32->64); staging sums nchunks partials
__global__ __launch_bounds__(256) void k_conv2(const float* __restrict__ c1p,
                                               const float* __restrict__ k2,
                                               float* __restrict__ c2,
                                               int nchunks) {
    __shared__ float sm[32 * 104];
    __shared__ __align__(16) float sk2[9 * 32 * 16];
    int t = threadIdx.x;
    int th = (blockIdx.x >> 3) * 8;
    int tw = (blockIdx.x & 7) * 8;
    int o0 = blockIdx.y * 16;
    for (int u = t; u < 3200; u += 256) {
        int i = u / 100;
        int pix = u % 100;
        int hh = th + pix / 10;
        int ww = tw + pix % 10;
        float v = 0.f;
        if (hh < 64 && ww < 64) {
            const float* p = c1p + (size_t)i * 4096 + hh * 64 + ww;
            for (int c = 0; c < nchunks; ++c)
                v += p[(size_t)c * 131072];
        }
        sm[i * 104 + pix] = v;
    }
    for (int u = t; u < 1152; u += 256) {
        int tap = u >> 7;
        int r = u & 127;
        int i = r >> 2, o4 = r & 3;
        *(float4*)&sk2[tap * 512 + i * 16 + o4 * 4] =
            *(const float4*)(k2 + (size_t)tap * 2048 + i * 64 + o0 + o4 * 4);
    }
    __syncthreads();
    int pix = t & 63;
    int lh = pix >> 3, lw = pix & 7, og = t >> 6;
    float acc[4] = {0.f, 0.f, 0.f, 0.f};
    for (int dh = 0; dh < 3; ++dh)
        for (int dw = 0; dw < 3; ++dw) {
            int pixb = (lh + dh) * 10 + (lw + dw);
            const float* kt = sk2 + (dh * 3 + dw) * 512 + og * 4;
            #pragma unroll 8
            for (int i = 0; i < 32; ++i) {
                float m = sm[i * 104 + pixb];
                float4 kv = *(const float4*)(kt + i * 16);
                acc[0] += m * kv.x; acc[1] += m * kv.y;
                acc[2] += m * kv.z; acc[3] += m * kv.w;
            }
        }
    int h = th + lh, w = tw + lw;
    if (h < 62 && w < 62) {
        #pragma unroll
        for (int j = 0; j < 4; ++j)
            c2[(size_t)(o0 + og * 4 + j) * 3844 + h * 62 + w] = acc[j];
    }
}

// ---- K3: r1p (blocks 0..930) + transpose (blocks 931..1186)
__global__ __launch_bounds__(256) void k_r1pt(const float* __restrict__ c2,
                                              const float* __restrict__ d1,
                                              float* __restrict__ p1,
                                              const float* __restrict__ mem,
                                              const int* __restrict__ px,
                                              const int* __restrict__ py,
                                              float* __restrict__ outm) {
    __shared__ __align__(16) float SM[4160];
    int t = threadIdx.x;
    int bid = blockIdx.x;
    if (bid < NB_R1) {
        float* pl   = SM;            // 256
        float* sred = SM + 256;      // [8][32][4]
        int f0 = bid * 256;
        int fmax = FLAT - f0; if (fmax > 256) fmax = 256;
        for (int s = t; s < fmax; s += 256) {
            int f = f0 + s;
            int o = f / 3721;
            int r = f % 3721;
            int h = r / 61, w = r % 61;
            const float* b = c2 + (size_t)o * 3844 + h * 62 + w;
            pl[s] = 0.25f * (b[0] + b[1] + b[62] + b[63]);
        }
        __syncthreads();
        int jq = t & 31, g = t >> 5;
        float4 a = make_float4(0.f, 0.f, 0.f, 0.f);
        for (int s = g; s < fmax; s += 8) {
            float m = pl[s];
            float4 dv = *(const float4*)(d1 + (size_t)(f0 + s) * 128 + jq * 4);
            a.x += m * dv.x; a.y += m * dv.y; a.z += m * dv.z; a.w += m * dv.w;
        }
        *(float4*)&sred[(g * 32 + jq) * 4] = a;
        __syncthreads();
        if (t < 32) {
            float4 s4 = make_float4(0.f, 0.f, 0.f, 0.f);
            #pragma unroll
            for (int gg = 0; gg < 8; ++gg) {
                float4 v = *(const float4*)&sred[(gg * 32 + t) * 4];
                s4.x += v.x; s4.y += v.y; s4.z += v.z; s4.w += v.w;
            }
            *(float4*)(p1 + (size_t)bid * 128 + t * 4) = s4;
        }
    } else {
        int tu = bid - NB_R1;
        float* tile = SM;            // [64][65]
        int p0 = (tu & 63) * 64;
        int u0 = (tu >> 6) * 64;
        int x = read_idx(px), y = read_idx(py);
        int pxy = x * 64 + y;
        int lane = t & 63, grp = t >> 6;
        for (int r = 0; r < 16; ++r) {
            int pr = grp + r * 4;
            tile[pr * 65 + lane] = mem[(size_t)(p0 + pr) * 256 + u0 + lane];
        }
        __syncthreads();
        for (int r = 0; r < 16; ++r) {
            int ur = grp + r * 4;
            if (p0 + lane != pxy)
                outm[(size_t)(u0 + ur) * 4096 + p0 + lane] = tile[lane * 65 + ur];
        }
    }
}

// ---- K4: fused r1 reduce + r_t / s_t / q_t (1 block x 1024; R16 numerics)
__global__ __launch_bounds__(1024) void k_fused(const float* __restrict__ p1,
                                                const float* __restrict__ d2,
                                                const float* __restrict__ inp,
                                                const float* __restrict__ ck,
                                                const float* __restrict__ rec,
                                                float* __restrict__ rt,
                                                float* __restrict__ qt,
                                                float* __restrict__ st) {
    __shared__ float p2s[8][128];
    __shared__ float s_r1[128], s_in[128], s_rt[256];
    int t = threadIdx.x;
    int j = t & 127, part = t >> 7;
    int b0 = part * 117;
    int b1 = b0 + 117; if (b1 > NB_R1) b1 = NB_R1;
    float s = 0.f;
    for (int b = b0; b < b1; ++b) s += p1[b * 128 + j];
    p2s[part][j] = s;
    if (t < 128) s_in[t] = inp[t];
    __syncthreads();
    if (t < 128) {
        float r = 0.f;
        #pragma unroll
        for (int c = 0; c < 8; ++c) r += p2s[c][t];
        s_r1[t] = r;
    }
    __syncthreads();
    if (t < 256) {
        float a = 0.f;
        for (int k = 0; k < 128; ++k) a += s_r1[k] * d2[k * 256 + t];
        rt[t] = a; s_rt[t] = a;
        float sv = 0.f;
        for (int k = 0; k < 128; ++k) sv += s_in[k] * rec[k * 256 + t];
        st[t] = sv;
    }
    __syncthreads();
    if (t < 256) {
        float q = 0.f;
        for (int k = 0; k < 128; ++k) q += s_in[k] * ck[k * 256 + t];
        for (int k = 0; k < 256; ++k) q += s_rt[k] * ck[(128 + k) * 256 + t];
        qt[t] = q;
    }
}

// ---- K5: scores + per-block stats (64 blocks x 256 thr, 64 rows/block)
__global__ __launch_bounds__(256) void k_scores(const float* __restrict__ qt,
                                                const float* __restrict__ mem,
                                                float* __restrict__ sc,
                                                float* __restrict__ stat) {
    __shared__ float q[256];
    __shared__ float rowv[64];
    int t = threadIdx.x;
    int bid = blockIdx.x;
    q[t] = qt[t];
    __syncthreads();
    int wave = t >> 6, lane = t & 63;
    float qx = q[lane * 4], qy = q[lane * 4 + 1],
          qz = q[lane * 4 + 2], qw = q[lane * 4 + 3];
    for (int r = 0; r < 16; ++r) {
        int p = bid * 64 + wave * 16 + r;
        float4 m = *(const float4*)(mem + (size_t)p * 256 + lane * 4);
        float acc = m.x * qx + m.y * qy + m.z * qz + m.w * qw;
        for (int off = 32; off; off >>= 1) acc += __shfl_down(acc, off);
        if (lane == 0) rowv[wave * 16 + r] = acc;
    }
    __syncthreads();
    if (t < 64) sc[bid * 64 + t] = rowv[t];
    if (t == 0) {
        float mb = rowv[0];
        for (int i = 1; i < 64; ++i) mb = fmaxf(mb, rowv[i]);
        float sb = 0.f;
        for (int i = 0; i < 64; ++i) sb += expf(rowv[i] - mb);
        stat[bid * 2]     = mb;
        stat[bid * 2 + 1] = sb;
    }
}

// ---- K6: softmax finalize + ctp partials (64 blocks, 64 rows each)
__global__ __launch_bounds__(256) void k_ctp(const float* __restrict__ stat,
                                             const float* __restrict__ sc,
                                             const float* __restrict__ mem,
                                             float* __restrict__ pc) {
    __shared__ float sm_[64], ss_[64], aux[2], aL[64];
    int t = threadIdx.x;
    int bid = blockIdx.x;
    if (t < 64) { sm_[t] = stat[t * 2]; ss_[t] = stat[t * 2 + 1]; }
    __syncthreads();
    if (t == 0) {
        float M = sm_[0];
        for (int i = 1; i < 64; ++i) M = fmaxf(M, sm_[i]);
        float S = 0.f;
        for (int i = 0; i < 64; ++i) S += ss_[i] * expf(sm_[i] - M);
        aux[0] = M; aux[1] = 1.f / S;
    }
    __syncthreads();
    float M = aux[0], invS = aux[1];
    int p0 = bid * 64;
    if (t < 64) aL[t] = expf(sc[p0 + t] - M) * invS;
    __syncthreads();
    float acc = 0.f;
    #pragma unroll 8
    for (int pp = 0; pp < 64; ++pp)
        acc += aL[pp] * mem[(size_t)(p0 + pp) * 256 + t];
    pc[bid * 256 + t] = acc;
}

// ---- K7: final (1 block; ct reduce folded, ascending block order)
__global__ __launch_bounds__(256) void k_final(const float* __restrict__ rt,
                                               const float* __restrict__ st,
                                               const float* __restrict__ pc,
                                               const float* __restrict__ mem,
                                               const float* __restrict__ rec,
                                               const int* __restrict__ px,
                                               const int* __restrict__ py,
                                               float* __restrict__ out) {
    __shared__ float s_diff[256], red[256];
    int t = threadIdx.x;
    int x = read_idx(px), y = read_idx(py);
    int pxy = x * 64 + y;
    float ctv = 0.f;
    #pragma unroll 8
    for (int b = 0; b < 64; ++b) ctv += pc[b * 256 + t];
    float stv = st[t], rtv = rt[t];
    float memt = mem[(size_t)pxy * 256 + t];
    red[t] = stv * rtv; __syncthreads();
    for (int s = 128; s; s >>= 1) { if (t < s) red[t] += red[t + s]; __syncthreads(); }
    float gimp = red[0]; __syncthreads();
    red[t] = stv * ctv; __syncthreads();
    for (int s = 128; s; s >>= 1) { if (t < s) red[t] += red[t + s]; __syncthreads(); }
    float limp = red[0];
    s_diff[t] = memt - stv;
    __syncthreads();
    float d = 0.f;
    for (int k = 0; k < 256; ++k)
        d += s_diff[k] * rec[(128 + k) * 256 + t];
    float frac = limp / (limp + gimp);
    out[t] = ctv;
    out[256 + t] = rtv;
    out[512 + (size_t)t * 4096 + pxy] = memt + frac * d;
}

// ---- fallback only: standalone transpose (runs LAST on scr path)
__global__ __launch_bounds__(256) void k_transpose(const float* __restrict__ mem,
                                                   const int* __restrict__ px,
                                                   const int* __restrict__ py,
                                                   float* __restrict__ outm) {
    __shared__ float tile[64][65];
    int t = threadIdx.x;
    int p0 = blockIdx.x * 64;
    int u0 = blockIdx.y * 64;
    int x = read_idx(px), y = read_idx(py);
    int pxy = x * 64 + y;
    int lane = t & 63, grp = t >> 6;
    for (int r = 0; r < 16; ++r) {
        int pr = grp + r * 4;
        tile[pr][lane] = mem[(size_t)(p0 + pr) * 256 + u0 + lane];
    }
    __syncthreads();
    for (int r = 0; r < 16; ++r) {
        int ur = grp + r * 4;
        if (p0 + lane != pxy)
            outm[(size_t)(u0 + ur) * 4096 + p0 + lane] = tile[lane][ur];
    }
}

extern "C" void kernel_launch(void* const* d_in, const int* in_sizes, int n_in,
                              void* d_out, int out_size, void* d_ws, size_t ws_size,
                              hipStream_t stream) {
    const float* inp = (const float*)d_in[0];
    const float* mem = (const float*)d_in[1];
    const float* k1  = (const float*)d_in[2];
    const float* k2  = (const float*)d_in[3];
    const float* d1  = (const float*)d_in[4];
    const float* d2  = (const float*)d_in[5];
    const float* ck  = (const float*)d_in[6];
    const float* rec = (const float*)d_in[7];
    const int* px = (const int*)d_in[8];
    const int* py = (const int*)d_in[9];
    float* out = (float*)d_out;
    float* scr = out + 512;
    float* ws  = (float*)d_ws;

    bool useWs = (ws != nullptr) && (ws_size >= (size_t)W_END * sizeof(float));

    if (useWs) {
        k_conv1<<<dim3(64, 8), 256, 0, stream>>>(mem, k1, scr);
        k_conv2<<<dim3(64, 4), 256, 0, stream>>>(scr, k2, ws + W_C2, 8);
        k_r1pt<<<NB_R1 + 256, 256, 0, stream>>>(ws + W_C2, d1, ws + W_P1,
                                                mem, px, py, scr);
        k_fused<<<1, 1024, 0, stream>>>(ws + W_P1, d2, inp, ck, rec,
                                        ws + W_RT, ws + W_QT, ws + W_ST);
        k_scores<<<64, 256, 0, stream>>>(ws + W_QT, mem, ws + W_SC,
                                         ws + W_STAT);
        k_ctp<<<64, 256, 0, stream>>>(ws + W_STAT, ws + W_SC, mem, ws + W_PC);
        k_final<<<1, 256, 0, stream>>>(ws + W_RT, ws + W_ST, ws + W_PC,
                                       mem, rec, px, py, out);
    } else {
        k_conv1<<<dim3(64, 8), 256, 0, stream>>>(mem, k1, scr);
        k_c1red<<<512, 256, 0, stream>>>(scr);
        k_conv2<<<dim3(64, 4), 256, 0, stream>>>(scr, k2, scr + F_C2, 1);
        k_r1pt<<<NB_R1, 256, 0, stream>>>(scr + F_C2, d1, scr + F_P1,
                                          mem, px, py, scr);
        k_fused<<<1, 1024, 0, stream>>>(scr + F_P1, d2, inp, ck, rec,
                                        scr + F_RT, scr + F_QT, scr + F_ST);
        k_scores<<<64, 256, 0, stream>>>(scr + F_QT, mem, scr + F_SC,
                                         scr + F_STAT);
        k_ctp<<<64, 256, 0, stream>>>(scr + F_STAT, scr + F_SC, mem,
                                      scr + F_PC);
        k_final<<<1, 256, 0, stream>>>(scr + F_RT, scr + F_ST, scr + F_PC,
                                       mem, rec, px, py, out);
        k_transpose<<<dim3(64, 4), 256, 0, stream>>>(mem, px, py, out + 512);
    }
}

// Round 7
// 326.056 us; speedup vs baseline: 1.6572x; 1.0700x over previous
//
#include <hip/hip_runtime.h>

// NeuralMapCell — ROUND 22. R20/R21 reconciliation: k_fused is ~60us of
// cold-HBM-miss latency (weights d2/rec/ck = 917KB first touched by ONE
// block; R20 counters: VALU 1.6%, HBM 0.9%, FETCH 6.5MB over 92us). Fix:
// (1) 16 warm blocks appended to k_r1pt stream-read d2+rec+ck concurrently
//     with the d1 stream -> weights L3-resident before k_fused/k_final;
// (2) order-preserving #pragma unroll in k_fused/k_final k-loops (load
//     pipelining, no reassociation);
// (3) transpose blocks first in r1pt (overlap, don't straggle);
// (4) r1p full-tile unrolled fast path (same order).
// Launches unchanged: 7 (ws path). absmax should be bit-identical to R21.
//
// d_out = float[1049088]: c_t[256] r_t[256] new_mem[1048576].
// scr = out + 512; c1p[8][32][4096] fills scr, dead after K2 (ws path), so
// K3's transpose overwrites scr with the real new_mem (skips pxy column).
#define FLAT  238144      // 64*61*61
#define NB_R1 931

// ws float offsets (ws path)
#define W_C2   0          // 246016
#define W_P1   246016     // 119168 -> 365184
#define W_RT   365184     // 256
#define W_ST   365440     // 256
#define W_QT   365696     // 256
#define W_SC   365952     // 4096
#define W_STAT 370048     // 128 (64 x {max,expsum})
#define W_PC   370176     // 16384 (64 x 256)
#define W_WARM 386560     // 16 (warm-block dummy sums)
#define W_END  386576

// scr float offsets (fallback path; transpose runs LAST, separately)
#define F_C2   140416
#define F_P1   386432     // -> 505600
#define F_RT   505600
#define F_ST   505856
#define F_QT   506112
#define F_SC   506368
#define F_STAT 510464
#define F_PC   510592     // -> 526976

__device__ __forceinline__ int read_idx(const int* p) {
    unsigned int u = (unsigned int)*p;
    int ex = (int)((u >> 23) & 0xFF);
    int v;
    if (ex >= 118 && ex <= 140) {
        union { unsigned int i; float f; } c; c.i = u;
        v = (int)(c.f + 0.5f);
    } else {
        v = (int)u;
    }
    return v < 0 ? 0 : (v > 63 ? 63 : v);
}

// ---- K1: conv1 (cross-corr, SAME, 3x3, 256->32): c1p[chunk][o][4096]
__global__ __launch_bounds__(256) void k_conv1(const float* __restrict__ mem,
                                               const float* __restrict__ k1,
                                               float* __restrict__ c1p) {
    __shared__ float sm[32 * 105];          // stride 105: staging banks spread
    __shared__ __align__(16) float sk[9 * 32 * 32];
    int t = threadIdx.x;
    int th = (blockIdx.x >> 3) * 8;
    int tw = (blockIdx.x & 7) * 8;
    int chunk = blockIdx.y;
    for (int u = t; u < 800; u += 256) {
        int pix = u >> 3;
        int c4 = u & 7;
        int hh = th - 1 + pix / 10;
        int ww = tw - 1 + pix % 10;
        float4 v = make_float4(0.f, 0.f, 0.f, 0.f);
        if ((unsigned)hh < 64u && (unsigned)ww < 64u)
            v = *(const float4*)(mem + (size_t)(hh * 64 + ww) * 256
                                     + chunk * 32 + c4 * 4);
        int ib = c4 * 4;
        sm[(ib    ) * 105 + pix] = v.x;
        sm[(ib + 1) * 105 + pix] = v.y;
        sm[(ib + 2) * 105 + pix] = v.z;
        sm[(ib + 3) * 105 + pix] = v.w;
    }
    for (int u = t; u < 2304; u += 256) {
        int tap = u >> 8;
        int r   = u & 255;
        const float4* src = (const float4*)(k1 + (size_t)tap * 8192
                                               + (size_t)chunk * 1024);
        *(float4*)&sk[tap * 1024 + r * 4] = src[r];
    }
    __syncthreads();
    int lh = (t & 63) >> 3, lw = t & 7, og = t >> 6;
    float acc[8];
    #pragma unroll
    for (int j = 0; j < 8; ++j) acc[j] = 0.f;
    for (int dh = 0; dh < 3; ++dh)
        for (int dw = 0; dw < 3; ++dw) {
            int pixb = (lh + dh) * 10 + (lw + dw);
            const float* kt = sk + (dh * 3 + dw) * 1024 + og * 8;
            #pragma unroll 4
            for (int i = 0; i < 32; ++i) {
                float m = sm[i * 105 + pixb];
                float4 ka = *(const float4*)(kt + i * 32);
                float4 kb = *(const float4*)(kt + i * 32 + 4);
                acc[0] += m * ka.x; acc[1] += m * ka.y;
                acc[2] += m * ka.z; acc[3] += m * ka.w;
                acc[4] += m * kb.x; acc[5] += m * kb.y;
                acc[6] += m * kb.z; acc[7] += m * kb.w;
            }
        }
    int p = (th + lh) * 64 + tw + lw;
    float* dst = c1p + (size_t)chunk * 131072 + (size_t)(og * 8) * 4096 + p;
    #pragma unroll
    for (int j = 0; j < 8; ++j)
        dst[(size_t)j * 4096] = acc[j];
}

// ---- fallback only: compact 8 chunk partials (ascending order)
__global__ __launch_bounds__(256) void k_c1red(float* __restrict__ c1p) {
    int idx = blockIdx.x * 256 + threadIdx.x;
    float s = 0.f;
    #pragma unroll
    for (int c = 0; c < 8; ++c) s += c1p[(size_t)c * 131072 + idx];
    c1p[idx] = s;
}

// ---- K2: conv2 (VALID, 3x3, 32->64); staging sums nchunks partials
__global__ __launch_bounds__(256) void k_conv2(const float* __restrict__ c1p,
                                               const float* __restrict__ k2,
                                               float* __restrict__ c2,
                                               int nchunks) {
    __shared__ float sm[32 * 104];
    __shared__ __align__(16) float sk2[9 * 32 * 16];
    int t = threadIdx.x;
    int th = (blockIdx.x >> 3) * 8;
    int tw = (blockIdx.x & 7) * 8;
    int o0 = blockIdx.y * 16;
    for (int u = t; u < 3200; u += 256) {
        int i = u / 100;
        int pix = u % 100;
        int hh = th + pix / 10;
        int ww = tw + pix % 10;
        float v = 0.f;
        if (hh < 64 && ww < 64) {
            const float* p = c1p + (size_t)i * 4096 + hh * 64 + ww;
            for (int c = 0; c < nchunks; ++c)
                v += p[(size_t)c * 131072];
        }
        sm[i * 104 + pix] = v;
    }
    for (int u = t; u < 1152; u += 256) {
        int tap = u >> 7;
        int r = u & 127;
        int i = r >> 2, o4 = r & 3;
        *(float4*)&sk2[tap * 512 + i * 16 + o4 * 4] =
            *(const float4*)(k2 + (size_t)tap * 2048 + i * 64 + o0 + o4 * 4);
    }
    __syncthreads();
    int pix = t & 63;
    int lh = pix >> 3, lw = pix & 7, og = t >> 6;
    float acc[4] = {0.f, 0.f, 0.f, 0.f};
    for (int dh = 0; dh < 3; ++dh)
        for (int dw = 0; dw < 3; ++dw) {
            int pixb = (lh + dh) * 10 + (lw + dw);
            const float* kt = sk2 + (dh * 3 + dw) * 512 + og * 4;
            #pragma unroll 8
            for (int i = 0; i < 32; ++i) {
                float m = sm[i * 104 + pixb];
                float4 kv = *(const float4*)(kt + i * 16);
                acc[0] += m * kv.x; acc[1] += m * kv.y;
                acc[2] += m * kv.z; acc[3] += m * kv.w;
            }
        }
    int h = th + lh, w = tw + lw;
    if (h < 62 && w < 62) {
        #pragma unroll
        for (int j = 0; j < 4; ++j)
            c2[(size_t)(o0 + og * 4 + j) * 3844 + h * 62 + w] = acc[j];
    }
}

// ---- K3: withx=1 (ws): [0..255]=transpose, [256..1186]=r1p, [1187..1202]=warm
//          withx=0 (fb): all blocks r1p (f-block = bid)
__global__ __launch_bounds__(256) void k_r1pt(const float* __restrict__ c2,
                                              const float* __restrict__ d1,
                                              float* __restrict__ p1,
                                              const float* __restrict__ mem,
                                              const int* __restrict__ px,
                                              const int* __restrict__ py,
                                              float* __restrict__ outm,
                                              const float* __restrict__ d2,
                                              const float* __restrict__ ck,
                                              const float* __restrict__ rec,
                                              float* __restrict__ warm,
                                              int withx) {
    __shared__ __align__(16) float SM[4160];
    int t = threadIdx.x;
    int bid = blockIdx.x;
    int fb = -1;                 // r1p f-block
    if (!withx) {
        fb = bid;
    } else if (bid < 256) {
        // ---- transpose unit (runs first, overlaps r1p stream)
        int tu = bid;
        float* tile = SM;            // [64][65]
        int p0 = (tu & 63) * 64;
        int u0 = (tu >> 6) * 64;
        int x = read_idx(px), y = read_idx(py);
        int pxy = x * 64 + y;
        int lane = t & 63, grp = t >> 6;
        for (int r = 0; r < 16; ++r) {
            int pr = grp + r * 4;
            tile[pr * 65 + lane] = mem[(size_t)(p0 + pr) * 256 + u0 + lane];
        }
        __syncthreads();
        for (int r = 0; r < 16; ++r) {
            int ur = grp + r * 4;
            if (p0 + lane != pxy)
                outm[(size_t)(u0 + ur) * 4096 + p0 + lane] = tile[lane * 65 + ur];
        }
        return;
    } else if (bid < 256 + NB_R1) {
        fb = bid - 256;
    } else {
        // ---- warm unit: stream d2(8192 f4) + rec(24576 f4) + ck(24576 f4)
        int wu = bid - (256 + NB_R1);      // 0..15
        float a = 0.f;
        for (int k = 0; k < 14; ++k) {
            int j = (wu * 256 + t) + k * 4096;   // 0..57343
            float4 v;
            if (j < 8192)        v = ((const float4*)d2 )[j];
            else if (j < 32768)  v = ((const float4*)rec)[j - 8192];
            else                 v = ((const float4*)ck )[j - 32768];
            a += v.x + v.y + v.z + v.w;
        }
        SM[t] = a;
        __syncthreads();
        if (t == 0) {
            float s = 0.f;
            for (int i = 0; i < 256; ++i) s += SM[i];
            warm[wu] = s;
        }
        return;
    }
    // ---- r1p unit
    {
        float* pl   = SM;            // 256
        float* sred = SM + 256;      // [8][32][4]
        int f0 = fb * 256;
        int fmax = FLAT - f0; if (fmax > 256) fmax = 256;
        for (int s = t; s < fmax; s += 256) {
            int f = f0 + s;
            int o = f / 3721;
            int r = f % 3721;
            int h = r / 61, w = r % 61;
            const float* b = c2 + (size_t)o * 3844 + h * 62 + w;
            pl[s] = 0.25f * (b[0] + b[1] + b[62] + b[63]);
        }
        __syncthreads();
        int jq = t & 31, g = t >> 5;
        float4 a = make_float4(0.f, 0.f, 0.f, 0.f);
        if (fmax == 256) {
            #pragma unroll 8
            for (int it = 0; it < 32; ++it) {
                int s = g + it * 8;
                float m = pl[s];
                float4 dv = *(const float4*)(d1 + (size_t)(f0 + s) * 128 + jq * 4);
                a.x += m * dv.x; a.y += m * dv.y; a.z += m * dv.z; a.w += m * dv.w;
            }
        } else {
            for (int s = g; s < fmax; s += 8) {
                float m = pl[s];
                float4 dv = *(const float4*)(d1 + (size_t)(f0 + s) * 128 + jq * 4);
                a.x += m * dv.x; a.y += m * dv.y; a.z += m * dv.z; a.w += m * dv.w;
            }
        }
        *(float4*)&sred[(g * 32 + jq) * 4] = a;
        __syncthreads();
        if (t < 32) {
            float4 s4 = make_float4(0.f, 0.f, 0.f, 0.f);
            #pragma unroll
            for (int gg = 0; gg < 8; ++gg) {
                float4 v = *(const float4*)&sred[(gg * 32 + t) * 4];
                s4.x += v.x; s4.y += v.y; s4.z += v.z; s4.w += v.w;
            }
            *(float4*)(p1 + (size_t)fb * 128 + t * 4) = s4;
        }
    }
}

// ---- K4: fused r1 reduce + r_t / s_t / q_t (1 block x 1024; R16 numerics,
// order-preserving unrolls for load pipelining)
__global__ __launch_bounds__(1024) void k_fused(const float* __restrict__ p1,
                                                const float* __restrict__ d2,
                                                const float* __restrict__ inp,
                                                const float* __restrict__ ck,
                                                const float* __restrict__ rec,
                                                float* __restrict__ rt,
                                                float* __restrict__ qt,
                                                float* __restrict__ st) {
    __shared__ float p2s[8][128];
    __shared__ float s_r1[128], s_in[128], s_rt[256];
    int t = threadIdx.x;
    int j = t & 127, part = t >> 7;
    int b0 = part * 117;
    int b1 = b0 + 117; if (b1 > NB_R1) b1 = NB_R1;
    float s = 0.f;
    #pragma unroll 4
    for (int b = b0; b < b1; ++b) s += p1[b * 128 + j];
    p2s[part][j] = s;
    if (t < 128) s_in[t] = inp[t];
    __syncthreads();
    if (t < 128) {
        float r = 0.f;
        #pragma unroll
        for (int c = 0; c < 8; ++c) r += p2s[c][t];
        s_r1[t] = r;
    }
    __syncthreads();
    if (t < 256) {
        float a = 0.f;
        #pragma unroll 8
        for (int k = 0; k < 128; ++k) a += s_r1[k] * d2[k * 256 + t];
        rt[t] = a; s_rt[t] = a;
        float sv = 0.f;
        #pragma unroll 8
        for (int k = 0; k < 128; ++k) sv += s_in[k] * rec[k * 256 + t];
        st[t] = sv;
    }
    __syncthreads();
    if (t < 256) {
        float q = 0.f;
        #pragma unroll 8
        for (int k = 0; k < 128; ++k) q += s_in[k] * ck[k * 256 + t];
        #pragma unroll 8
        for (int k = 0; k < 256; ++k) q += s_rt[k] * ck[(128 + k) * 256 + t];
        qt[t] = q;
    }
}

// ---- K5: scores + per-block stats (64 blocks x 256 thr, 64 rows/block)
__global__ __launch_bounds__(256) void k_scores(const float* __restrict__ qt,
                                                const float* __restrict__ mem,
                                                float* __restrict__ sc,
                                                float* __restrict__ stat) {
    __shared__ float q[256];
    __shared__ float rowv[64];
    int t = threadIdx.x;
    int bid = blockIdx.x;
    q[t] = qt[t];
    __syncthreads();
    int wave = t >> 6, lane = t & 63;
    float qx = q[lane * 4], qy = q[lane * 4 + 1],
          qz = q[lane * 4 + 2], qw = q[lane * 4 + 3];
    for (int r = 0; r < 16; ++r) {
        int p = bid * 64 + wave * 16 + r;
        float4 m = *(const float4*)(mem + (size_t)p * 256 + lane * 4);
        float acc = m.x * qx + m.y * qy + m.z * qz + m.w * qw;
        for (int off = 32; off; off >>= 1) acc += __shfl_down(acc, off);
        if (lane == 0) rowv[wave * 16 + r] = acc;
    }
    __syncthreads();
    if (t < 64) sc[bid * 64 + t] = rowv[t];
    if (t == 0) {
        float mb = rowv[0];
        for (int i = 1; i < 64; ++i) mb = fmaxf(mb, rowv[i]);
        float sb = 0.f;
        for (int i = 0; i < 64; ++i) sb += expf(rowv[i] - mb);
        stat[bid * 2]     = mb;
        stat[bid * 2 + 1] = sb;
    }
}

// ---- K6: softmax finalize + ctp partials (64 blocks, 64 rows each)
__global__ __launch_bounds__(256) void k_ctp(const float* __restrict__ stat,
                                             const float* __restrict__ sc,
                                             const float* __restrict__ mem,
                                             float* __restrict__ pc) {
    __shared__ float sm_[64], ss_[64], aux[2], aL[64];
    int t = threadIdx.x;
    int bid = blockIdx.x;
    if (t < 64) { sm_[t] = stat[t * 2]; ss_[t] = stat[t * 2 + 1]; }
    __syncthreads();
    if (t == 0) {
        float M = sm_[0];
        for (int i = 1; i < 64; ++i) M = fmaxf(M, sm_[i]);
        float S = 0.f;
        for (int i = 0; i < 64; ++i) S += ss_[i] * expf(sm_[i] - M);
        aux[0] = M; aux[1] = 1.f / S;
    }
    __syncthreads();
    float M = aux[0], invS = aux[1];
    int p0 = bid * 64;
    if (t < 64) aL[t] = expf(sc[p0 + t] - M) * invS;
    __syncthreads();
    float acc = 0.f;
    #pragma unroll 8
    for (int pp = 0; pp < 64; ++pp)
        acc += aL[pp] * mem[(size_t)(p0 + pp) * 256 + t];
    pc[bid * 256 + t] = acc;
}

// ---- K7: final (1 block; ct reduce folded, ascending block order)
__global__ __launch_bounds__(256) void k_final(const float* __restrict__ rt,
                                               const float* __restrict__ st,
                                               const float* __restrict__ pc,
                                               const float* __restrict__ mem,
                                               const float* __restrict__ rec,
                                               const int* __restrict__ px,
                                               const int* __restrict__ py,
                                               float* __restrict__ out) {
    __shared__ float s_diff[256], red[256];
    int t = threadIdx.x;
    int x = read_idx(px), y = read_idx(py);
    int pxy = x * 64 + y;
    float ctv = 0.f;
    #pragma unroll 8
    for (int b = 0; b < 64; ++b) ctv += pc[b * 256 + t];
    float stv = st[t], rtv = rt[t];
    float memt = mem[(size_t)pxy * 256 + t];
    red[t] = stv * rtv; __syncthreads();
    for (int s = 128; s; s >>= 1) { if (t < s) red[t] += red[t + s]; __syncthreads(); }
    float gimp = red[0]; __syncthreads();
    red[t] = stv * ctv; __syncthreads();
    for (int s = 128; s; s >>= 1) { if (t < s) red[t] += red[t + s]; __syncthreads(); }
    float limp = red[0];
    s_diff[t] = memt - stv;
    __syncthreads();
    float d = 0.f;
    #pragma unroll 8
    for (int k = 0; k < 256; ++k)
        d += s_diff[k] * rec[(128 + k) * 256 + t];
    float frac = limp / (limp + gimp);
    out[t] = ctv;
    out[256 + t] = rtv;
    out[512 + (size_t)t * 4096 + pxy] = memt + frac * d;
}

// ---- fallback only: standalone transpose (runs LAST on scr path)
__global__ __launch_bounds__(256) void k_transpose(const float* __restrict__ mem,
                                                   const int* __restrict__ px,
                                                   const int* __restrict__ py,
                                                   float* __restrict__ outm) {
    __shared__ float tile[64][65];
    int t = threadIdx.x;
    int p0 = blockIdx.x * 64;
    int u0 = blockIdx.y * 64;
    int x = read_idx(px), y = read_idx(py);
    int pxy = x * 64 + y;
    int lane = t & 63, grp = t >> 6;
    for (int r = 0; r < 16; ++r) {
        int pr = grp + r * 4;
        tile[pr][lane] = mem[(size_t)(p0 + pr) * 256 + u0 + lane];
    }
    __syncthreads();
    for (int r = 0; r < 16; ++r) {
        int ur = grp + r * 4;
        if (p0 + lane != pxy)
            outm[(size_t)(u0 + ur) * 4096 + p0 + lane] = tile[lane][ur];
    }
}

extern "C" void kernel_launch(void* const* d_in, const int* in_sizes, int n_in,
                              void* d_out, int out_size, void* d_ws, size_t ws_size,
                              hipStream_t stream) {
    const float* inp = (const float*)d_in[0];
    const float* mem = (const float*)d_in[1];
    const float* k1  = (const float*)d_in[2];
    const float* k2  = (const float*)d_in[3];
    const float* d1  = (const float*)d_in[4];
    const float* d2  = (const float*)d_in[5];
    const float* ck  = (const float*)d_in[6];
    const float* rec = (const float*)d_in[7];
    const int* px = (const int*)d_in[8];
    const int* py = (const int*)d_in[9];
    float* out = (float*)d_out;
    float* scr = out + 512;
    float* ws  = (float*)d_ws;

    bool useWs = (ws != nullptr) && (ws_size >= (size_t)W_END * sizeof(float));

    if (useWs) {
        k_conv1<<<dim3(64, 8), 256, 0, stream>>>(mem, k1, scr);
        k_conv2<<<dim3(64, 4), 256, 0, stream>>>(scr, k2, ws + W_C2, 8);
        k_r1pt<<<256 + NB_R1 + 16, 256, 0, stream>>>(ws + W_C2, d1, ws + W_P1,
                                                     mem, px, py, scr,
                                                     d2, ck, rec,
                                                     ws + W_WARM, 1);
        k_fused<<<1, 1024, 0, stream>>>(ws + W_P1, d2, inp, ck, rec,
                                        ws + W_RT, ws + W_QT, ws + W_ST);
        k_scores<<<64, 256, 0, stream>>>(ws + W_QT, mem, ws + W_SC,
                                         ws + W_STAT);
        k_ctp<<<64, 256, 0, stream>>>(ws + W_STAT, ws + W_SC, mem, ws + W_PC);
        k_final<<<1, 256, 0, stream>>>(ws + W_RT, ws + W_ST, ws + W_PC,
                                       mem, rec, px, py, out);
    } else {
        k_conv1<<<dim3(64, 8), 256, 0, stream>>>(mem, k1, scr);
        k_c1red<<<512, 256, 0, stream>>>(scr);
        k_conv2<<<dim3(64, 4), 256, 0, stream>>>(scr, k2, scr + F_C2, 1);
        k_r1pt<<<NB_R1, 256, 0, stream>>>(scr + F_C2, d1, scr + F_P1,
                                          mem, px, py, scr,
                                          d2, ck, rec, scr + F_PC + 16384, 0);
        k_fused<<<1, 1024, 0, stream>>>(scr + F_P1, d2, inp, ck, rec,
                                        scr + F_RT, scr + F_QT, scr + F_ST);
        k_scores<<<64, 256, 0, stream>>>(scr + F_QT, mem, scr + F_SC,
                                         scr + F_STAT);
        k_ctp<<<64, 256, 0, stream>>>(scr + F_STAT, scr + F_SC, mem,
                                      scr + F_PC);
        k_final<<<1, 256, 0, stream>>>(scr + F_RT, scr + F_ST, scr + F_PC,
                                       mem, rec, px, py, out);
        k_transpose<<<dim3(64, 4), 256, 0, stream>>>(mem, px, py, out + 512);
    }
}

// Round 9
// 314.620 us; speedup vs baseline: 1.7174x; 1.0363x over previous
//
#include <hip/hip_runtime.h>

// NeuralMapCell — ROUND 24. R23 resubmit, unchanged after full hazard audit
// (no atomics/tickets/coop; uniform barriers; all indices bounds-checked) —
// R23's "container failed twice" attributed to infra flake (cf. R19->R20
// precedent and harness timing instability). If this fails again, the
// structure is flagged toxic and next round reverts to R22+hoist-only.
//   (1) flash-merge ctp into scores: each scores block computes
//       UNNORMALIZED partial PV over its 64 rows (mem rows L1/L2-hot);
//       final rescales by e^{mb-M}/S. Kernel+gap deleted.
//   (2) st and qta(=inp@ck[:128]) hoisted into r1pt blocks (bit-identical
//       order; warms rec/ck rows 0..127 through use). k_fused keeps
//       r1-reduce + rt + qt second half (identical add sequence).
// 6 launches (ws path). Banned: grid.sync, tickets, redundant heavy compute.
//
// d_out = float[1049088]: c_t[256] r_t[256] new_mem[1048576].
// scr = out + 512; c1p[8][32][4096] fills scr, dead after K2 (ws path), so
// K3's transpose overwrites scr with the real new_mem (skips pxy column).
#define FLAT  238144      // 64*61*61
#define NB_R1 931

// ws float offsets (ws path)
#define W_C2   0          // 246016
#define W_P1   246016     // 119168 -> 365184
#define W_RT   365184     // 256
#define W_ST   365440     // 256
#define W_QT   365696     // 256
#define W_QTA  365952     // 256
#define W_STAT 366208     // 128 (64 x {max,expsum})
#define W_PC   366336     // 16384 (64 x 256) unnormalized partial PV
#define W_WARM 382720     // 16
#define W_END  382736

// scr float offsets (fallback path; transpose runs LAST, separately)
#define F_C2   140416
#define F_P1   386432     // -> 505600
#define F_RT   505600
#define F_ST   505856
#define F_QT   506112
#define F_QTA  506368
#define F_STAT 510464
#define F_PC   510592     // -> 526976

__device__ __forceinline__ int read_idx(const int* p) {
    unsigned int u = (unsigned int)*p;
    int ex = (int)((u >> 23) & 0xFF);
    int v;
    if (ex >= 118 && ex <= 140) {
        union { unsigned int i; float f; } c; c.i = u;
        v = (int)(c.f + 0.5f);
    } else {
        v = (int)u;
    }
    return v < 0 ? 0 : (v > 63 ? 63 : v);
}

// ---- K1: conv1 (cross-corr, SAME, 3x3, 256->32): c1p[chunk][o][4096]
__global__ __launch_bounds__(256) void k_conv1(const float* __restrict__ mem,
                                               const float* __restrict__ k1,
                                               float* __restrict__ c1p) {
    __shared__ float sm[32 * 105];
    __shared__ __align__(16) float sk[9 * 32 * 32];
    int t = threadIdx.x;
    int th = (blockIdx.x >> 3) * 8;
    int tw = (blockIdx.x & 7) * 8;
    int chunk = blockIdx.y;
    for (int u = t; u < 800; u += 256) {
        int pix = u >> 3;
        int c4 = u & 7;
        int hh = th - 1 + pix / 10;
        int ww = tw - 1 + pix % 10;
        float4 v = make_float4(0.f, 0.f, 0.f, 0.f);
        if ((unsigned)hh < 64u && (unsigned)ww < 64u)
            v = *(const float4*)(mem + (size_t)(hh * 64 + ww) * 256
                                     + chunk * 32 + c4 * 4);
        int ib = c4 * 4;
        sm[(ib    ) * 105 + pix] = v.x;
        sm[(ib + 1) * 105 + pix] = v.y;
        sm[(ib + 2) * 105 + pix] = v.z;
        sm[(ib + 3) * 105 + pix] = v.w;
    }
    for (int u = t; u < 2304; u += 256) {
        int tap = u >> 8;
        int r   = u & 255;
        const float4* src = (const float4*)(k1 + (size_t)tap * 8192
                                               + (size_t)chunk * 1024);
        *(float4*)&sk[tap * 1024 + r * 4] = src[r];
    }
    __syncthreads();
    int lh = (t & 63) >> 3, lw = t & 7, og = t >> 6;
    float acc[8];
    #pragma unroll
    for (int j = 0; j < 8; ++j) acc[j] = 0.f;
    for (int dh = 0; dh < 3; ++dh)
        for (int dw = 0; dw < 3; ++dw) {
            int pixb = (lh + dh) * 10 + (lw + dw);
            const float* kt = sk + (dh * 3 + dw) * 1024 + og * 8;
            #pragma unroll 4
            for (int i = 0; i < 32; ++i) {
                float m = sm[i * 105 + pixb];
                float4 ka = *(const float4*)(kt + i * 32);
                float4 kb = *(const float4*)(kt + i * 32 + 4);
                acc[0] += m * ka.x; acc[1] += m * ka.y;
                acc[2] += m * ka.z; acc[3] += m * ka.w;
                acc[4] += m * kb.x; acc[5] += m * kb.y;
                acc[6] += m * kb.z; acc[7] += m * kb.w;
            }
        }
    int p = (th + lh) * 64 + tw + lw;
    float* dst = c1p + (size_t)chunk * 131072 + (size_t)(og * 8) * 4096 + p;
    #pragma unroll
    for (int j = 0; j < 8; ++j)
        dst[(size_t)j * 4096] = acc[j];
}

// ---- fallback only: compact 8 chunk partials (ascending order)
__global__ __launch_bounds__(256) void k_c1red(float* __restrict__ c1p) {
    int idx = blockIdx.x * 256 + threadIdx.x;
    float s = 0.f;
    #pragma unroll
    for (int c = 0; c < 8; ++c) s += c1p[(size_t)c * 131072 + idx];
    c1p[idx] = s;
}

// ---- K2: conv2 (VALID, 3x3, 32->64); staging sums nchunks partials
__global__ __launch_bounds__(256) void k_conv2(const float* __restrict__ c1p,
                                               const float* __restrict__ k2,
                                               float* __restrict__ c2,
                                               int nchunks) {
    __shared__ float sm[32 * 104];
    __shared__ __align__(16) float sk2[9 * 32 * 16];
    int t = threadIdx.x;
    int th = (blockIdx.x >> 3) * 8;
    int tw = (blockIdx.x & 7) * 8;
    int o0 = blockIdx.y * 16;
    for (int u = t; u < 3200; u += 256) {
        int i = u / 100;
        int pix = u % 100;
        int hh = th + pix / 10;
        int ww = tw + pix % 10;
        float v = 0.f;
        if (hh < 64 && ww < 64) {
            const float* p = c1p + (size_t)i * 4096 + hh * 64 + ww;
            for (int c = 0; c < nchunks; ++c)
                v += p[(size_t)c * 131072];
        }
        sm[i * 104 + pix] = v;
    }
    for (int u = t; u < 1152; u += 256) {
        int tap = u >> 7;
        int r = u & 127;
        int i = r >> 2, o4 = r & 3;
        *(float4*)&sk2[tap * 512 + i * 16 + o4 * 4] =
            *(const float4*)(k2 + (size_t)tap * 2048 + i * 64 + o0 + o4 * 4);
    }
    __syncthreads();
    int pix = t & 63;
    int lh = pix >> 3, lw = pix & 7, og = t >> 6;
    float acc[4] = {0.f, 0.f, 0.f, 0.f};
    for (int dh = 0; dh < 3; ++dh)
        for (int dw = 0; dw < 3; ++dw) {
            int pixb = (lh + dh) * 10 + (lw + dw);
            const float* kt = sk2 + (dh * 3 + dw) * 512 + og * 4;
            #pragma unroll 8
            for (int i = 0; i < 32; ++i) {
                float m = sm[i * 104 + pixb];
                float4 kv = *(const float4*)(kt + i * 16);
                acc[0] += m * kv.x; acc[1] += m * kv.y;
                acc[2] += m * kv.z; acc[3] += m * kv.w;
            }
        }
    int h = th + lh, w = tw + lw;
    if (h < 62 && w < 62) {
        #pragma unroll
        for (int j = 0; j < 4; ++j)
            c2[(size_t)(o0 + og * 4 + j) * 3844 + h * 62 + w] = acc[j];
    }
}

// ---- K3: withx=1 (ws): [0..255]=transpose, [256..1186]=r1p,
//      [1187]=st, [1188]=qta, [1189..1202]=warm-stream d2/rec2/ck2.
//      withx=0 (fb): all blocks r1p.
__global__ __launch_bounds__(256) void k_r1pt(const float* __restrict__ c2,
                                              const float* __restrict__ d1,
                                              float* __restrict__ p1,
                                              const float* __restrict__ mem,
                                              const int* __restrict__ px,
                                              const int* __restrict__ py,
                                              float* __restrict__ outm,
                                              const float* __restrict__ d2,
                                              const float* __restrict__ ck,
                                              const float* __restrict__ rec,
                                              const float* __restrict__ inp,
                                              float* __restrict__ st,
                                              float* __restrict__ qta,
                                              float* __restrict__ warm,
                                              int withx) {
    __shared__ __align__(16) float SM[4160];
    int t = threadIdx.x;
    int bid = blockIdx.x;
    int fb = -1;
    if (!withx) {
        fb = bid;
    } else if (bid < 256) {
        // ---- transpose unit
        int tu = bid;
        float* tile = SM;            // [64][65]
        int p0 = (tu & 63) * 64;
        int u0 = (tu >> 6) * 64;
        int x = read_idx(px), y = read_idx(py);
        int pxy = x * 64 + y;
        int lane = t & 63, grp = t >> 6;
        for (int r = 0; r < 16; ++r) {
            int pr = grp + r * 4;
            tile[pr * 65 + lane] = mem[(size_t)(p0 + pr) * 256 + u0 + lane];
        }
        __syncthreads();
        for (int r = 0; r < 16; ++r) {
            int ur = grp + r * 4;
            if (p0 + lane != pxy)
                outm[(size_t)(u0 + ur) * 4096 + p0 + lane] = tile[lane * 65 + ur];
        }
        return;
    } else if (bid < 256 + NB_R1) {
        fb = bid - 256;
    } else if (bid == 256 + NB_R1) {
        // ---- st = inp @ rec[:128]  (bit-identical order; warms rec rows 0..127)
        float sv = 0.f;
        #pragma unroll 8
        for (int k = 0; k < 128; ++k) sv += inp[k] * rec[k * 256 + t];
        st[t] = sv;
        return;
    } else if (bid == 257 + NB_R1) {
        // ---- qta = inp @ ck[:128]  (bit-identical prefix of qt)
        float q = 0.f;
        #pragma unroll 8
        for (int k = 0; k < 128; ++k) q += inp[k] * ck[k * 256 + t];
        qta[t] = q;
        return;
    } else {
        // ---- warm: d2 (f4 0..8191), rec rows 128..383 (f4 8192..24575),
        //            ck rows 128..383 (f4 j-16384 in 8192..24575)
        int wu = bid - (258 + NB_R1);      // 0..13
        float a = 0.f;
        for (int k = 0; k < 12; ++k) {
            int j = (wu * 256 + t) + k * 3584;
            if (j < 40960) {
                float4 v;
                if (j < 8192)        v = ((const float4*)d2 )[j];
                else if (j < 24576)  v = ((const float4*)rec)[j];
                else                 v = ((const float4*)ck )[j - 16384];
                a += v.x + v.y + v.z + v.w;
            }
        }
        SM[t] = a;
        __syncthreads();
        if (t == 0) {
            float s = 0.f;
            for (int i = 0; i < 256; ++i) s += SM[i];
            warm[wu] = s;
        }
        return;
    }
    // ---- r1p unit
    {
        float* pl   = SM;
        float* sred = SM + 256;
        int f0 = fb * 256;
        int fmax = FLAT - f0; if (fmax > 256) fmax = 256;
        for (int s = t; s < fmax; s += 256) {
            int f = f0 + s;
            int o = f / 3721;
            int r = f % 3721;
            int h = r / 61, w = r % 61;
            const float* b = c2 + (size_t)o * 3844 + h * 62 + w;
            pl[s] = 0.25f * (b[0] + b[1] + b[62] + b[63]);
        }
        __syncthreads();
        int jq = t & 31, g = t >> 5;
        float4 a = make_float4(0.f, 0.f, 0.f, 0.f);
        if (fmax == 256) {
            #pragma unroll 8
            for (int it = 0; it < 32; ++it) {
                int s = g + it * 8;
                float m = pl[s];
                float4 dv = *(const float4*)(d1 + (size_t)(f0 + s) * 128 + jq * 4);
                a.x += m * dv.x; a.y += m * dv.y; a.z += m * dv.z; a.w += m * dv.w;
            }
        } else {
            for (int s = g; s < fmax; s += 8) {
                float m = pl[s];
                float4 dv = *(const float4*)(d1 + (size_t)(f0 + s) * 128 + jq * 4);
                a.x += m * dv.x; a.y += m * dv.y; a.z += m * dv.z; a.w += m * dv.w;
            }
        }
        *(float4*)&sred[(g * 32 + jq) * 4] = a;
        __syncthreads();
        if (t < 32) {
            float4 s4 = make_float4(0.f, 0.f, 0.f, 0.f);
            #pragma unroll
            for (int gg = 0; gg < 8; ++gg) {
                float4 v = *(const float4*)&sred[(gg * 32 + t) * 4];
                s4.x += v.x; s4.y += v.y; s4.z += v.z; s4.w += v.w;
            }
            *(float4*)(p1 + (size_t)fb * 128 + t * 4) = s4;
        }
    }
}

// ---- K4: fused r1 reduce + rt + qt-tail. haveAux=1: st/qta precomputed.
__global__ __launch_bounds__(1024) void k_fused(const float* __restrict__ p1,
                                                const float* __restrict__ d2,
                                                const float* __restrict__ inp,
                                                const float* __restrict__ ck,
                                                const float* __restrict__ rec,
                                                const float* __restrict__ qta,
                                                float* __restrict__ rt,
                                                float* __restrict__ qt,
                                                float* __restrict__ st,
                                                int haveAux) {
    __shared__ float p2s[8][128];
    __shared__ float s_r1[128], s_in[128], s_rt[256];
    int t = threadIdx.x;
    int j = t & 127, part = t >> 7;
    int b0 = part * 117;
    int b1 = b0 + 117; if (b1 > NB_R1) b1 = NB_R1;
    float s = 0.f;
    #pragma unroll 4
    for (int b = b0; b < b1; ++b) s += p1[b * 128 + j];
    p2s[part][j] = s;
    if (t < 128) s_in[t] = inp[t];
    __syncthreads();
    if (t < 128) {
        float r = 0.f;
        #pragma unroll
        for (int c = 0; c < 8; ++c) r += p2s[c][t];
        s_r1[t] = r;
    }
    __syncthreads();
    if (t < 256) {
        float a = 0.f;
        #pragma unroll 8
        for (int k = 0; k < 128; ++k) a += s_r1[k] * d2[k * 256 + t];
        rt[t] = a; s_rt[t] = a;
        if (!haveAux) {
            float sv = 0.f;
            #pragma unroll 8
            for (int k = 0; k < 128; ++k) sv += s_in[k] * rec[k * 256 + t];
            st[t] = sv;
        }
    }
    __syncthreads();
    if (t < 256) {
        float q;
        if (haveAux) {
            q = qta[t];
        } else {
            q = 0.f;
            #pragma unroll 8
            for (int k = 0; k < 128; ++k) q += s_in[k] * ck[k * 256 + t];
        }
        #pragma unroll 8
        for (int k = 0; k < 256; ++k) q += s_rt[k] * ck[(128 + k) * 256 + t];
        qt[t] = q;
    }
}

// ---- K5: scores + stats + UNNORMALIZED partial PV (64 blocks, 64 rows each)
__global__ __launch_bounds__(256) void k_scores(const float* __restrict__ qt,
                                                const float* __restrict__ mem,
                                                float* __restrict__ stat,
                                                float* __restrict__ pc) {
    __shared__ float q[256];
    __shared__ float rowv[64], aL[64];
    __shared__ float mbS;
    int t = threadIdx.x;
    int bid = blockIdx.x;
    q[t] = qt[t];
    __syncthreads();
    int wave = t >> 6, lane = t & 63;
    float qx = q[lane * 4], qy = q[lane * 4 + 1],
          qz = q[lane * 4 + 2], qw = q[lane * 4 + 3];
    int p0 = bid * 64;
    for (int r = 0; r < 16; ++r) {
        int p = p0 + wave * 16 + r;
        float4 m = *(const float4*)(mem + (size_t)p * 256 + lane * 4);
        float acc = m.x * qx + m.y * qy + m.z * qz + m.w * qw;
        for (int off = 32; off; off >>= 1) acc += __shfl_down(acc, off);
        if (lane == 0) rowv[wave * 16 + r] = acc;
    }
    __syncthreads();
    if (t == 0) {
        float mb = rowv[0];
        for (int i = 1; i < 64; ++i) mb = fmaxf(mb, rowv[i]);
        mbS = mb;
    }
    __syncthreads();
    if (t < 64) aL[t] = expf(rowv[t] - mbS);
    __syncthreads();
    if (t == 0) {
        float sb = 0.f;
        for (int i = 0; i < 64; ++i) sb += aL[i];
        stat[bid * 2]     = mbS;
        stat[bid * 2 + 1] = sb;
    }
    // unnormalized partial PV over this block's 64 rows (mem rows L1/L2-hot)
    float acc = 0.f;
    #pragma unroll 8
    for (int pp = 0; pp < 64; ++pp)
        acc += aL[pp] * mem[(size_t)(p0 + pp) * 256 + t];
    pc[bid * 256 + t] = acc;
}

// ---- K6: final (1 block; global softmax rescale + ct + mem update)
__global__ __launch_bounds__(256) void k_final(const float* __restrict__ rt,
                                               const float* __restrict__ st,
                                               const float* __restrict__ stat,
                                               const float* __restrict__ pc,
                                               const float* __restrict__ mem,
                                               const float* __restrict__ rec,
                                               const int* __restrict__ px,
                                               const int* __restrict__ py,
                                               float* __restrict__ out) {
    __shared__ float s_diff[256], red[256];
    __shared__ float sm_[64], wb[64], aux[2];
    int t = threadIdx.x;
    int x = read_idx(px), y = read_idx(py);
    int pxy = x * 64 + y;
    if (t < 64) sm_[t] = stat[t * 2];
    __syncthreads();
    if (t == 0) {
        float M = sm_[0];
        for (int i = 1; i < 64; ++i) M = fmaxf(M, sm_[i]);
        float S = 0.f;
        for (int i = 0; i < 64; ++i) S += stat[i * 2 + 1] * expf(sm_[i] - M);
        aux[0] = M; aux[1] = 1.f / S;
    }
    __syncthreads();
    if (t < 64) wb[t] = expf(sm_[t] - aux[0]) * aux[1];
    __syncthreads();
    float ctv = 0.f;
    #pragma unroll 8
    for (int b = 0; b < 64; ++b) ctv += pc[b * 256 + t] * wb[b];
    float stv = st[t], rtv = rt[t];
    float memt = mem[(size_t)pxy * 256 + t];
    red[t] = stv * rtv; __syncthreads();
    for (int s = 128; s; s >>= 1) { if (t < s) red[t] += red[t + s]; __syncthreads(); }
    float gimp = red[0]; __syncthreads();
    red[t] = stv * ctv; __syncthreads();
    for (int s = 128; s; s >>= 1) { if (t < s) red[t] += red[t + s]; __syncthreads(); }
    float limp = red[0];
    s_diff[t] = memt - stv;
    __syncthreads();
    float d = 0.f;
    #pragma unroll 8
    for (int k = 0; k < 256; ++k)
        d += s_diff[k] * rec[(128 + k) * 256 + t];
    float frac = limp / (limp + gimp);
    out[t] = ctv;
    out[256 + t] = rtv;
    out[512 + (size_t)t * 4096 + pxy] = memt + frac * d;
}

// ---- fallback only: standalone transpose (runs LAST on scr path)
__global__ __launch_bounds__(256) void k_transpose(const float* __restrict__ mem,
                                                   const int* __restrict__ px,
                                                   const int* __restrict__ py,
                                                   float* __restrict__ outm) {
    __shared__ float tile[64][65];
    int t = threadIdx.x;
    int p0 = blockIdx.x * 64;
    int u0 = blockIdx.y * 64;
    int x = read_idx(px), y = read_idx(py);
    int pxy = x * 64 + y;
    int lane = t & 63, grp = t >> 6;
    for (int r = 0; r < 16; ++r) {
        int pr = grp + r * 4;
        tile[pr][lane] = mem[(size_t)(p0 + pr) * 256 + u0 + lane];
    }
    __syncthreads();
    for (int r = 0; r < 16; ++r) {
        int ur = grp + r * 4;
        if (p0 + lane != pxy)
            outm[(size_t)(u0 + ur) * 4096 + p0 + lane] = tile[lane][ur];
    }
}

extern "C" void kernel_launch(void* const* d_in, const int* in_sizes, int n_in,
                              void* d_out, int out_size, void* d_ws, size_t ws_size,
                              hipStream_t stream) {
    const float* inp = (const float*)d_in[0];
    const float* mem = (const float*)d_in[1];
    const float* k1  = (const float*)d_in[2];
    const float* k2  = (const float*)d_in[3];
    const float* d1  = (const float*)d_in[4];
    const float* d2  = (const float*)d_in[5];
    const float* ck  = (const float*)d_in[6];
    const float* rec = (const float*)d_in[7];
    const int* px = (const int*)d_in[8];
    const int* py = (const int*)d_in[9];
    float* out = (float*)d_out;
    float* scr = out + 512;
    float* ws  = (float*)d_ws;

    bool useWs = (ws != nullptr) && (ws_size >= (size_t)W_END * sizeof(float));

    if (useWs) {
        k_conv1<<<dim3(64, 8), 256, 0, stream>>>(mem, k1, scr);
        k_conv2<<<dim3(64, 4), 256, 0, stream>>>(scr, k2, ws + W_C2, 8);
        k_r1pt<<<256 + NB_R1 + 16, 256, 0, stream>>>(
            ws + W_C2, d1, ws + W_P1, mem, px, py, scr,
            d2, ck, rec, inp, ws + W_ST, ws + W_QTA, ws + W_WARM, 1);
        k_fused<<<1, 1024, 0, stream>>>(ws + W_P1, d2, inp, ck, rec,
                                        ws + W_QTA, ws + W_RT, ws + W_QT,
                                        ws + W_ST, 1);
        k_scores<<<64, 256, 0, stream>>>(ws + W_QT, mem, ws + W_STAT,
                                         ws + W_PC);
        k_final<<<1, 256, 0, stream>>>(ws + W_RT, ws + W_ST, ws + W_STAT,
                                       ws + W_PC, mem, rec, px, py, out);
    } else {
        k_conv1<<<dim3(64, 8), 256, 0, stream>>>(mem, k1, scr);
        k_c1red<<<512, 256, 0, stream>>>(scr);
        k_conv2<<<dim3(64, 4), 256, 0, stream>>>(scr, k2, scr + F_C2, 1);
        k_r1pt<<<NB_R1, 256, 0, stream>>>(
            scr + F_C2, d1, scr + F_P1, mem, px, py, scr,
            d2, ck, rec, inp, scr + F_ST, scr + F_QTA, scr + F_PC + 16384, 0);
        k_fused<<<1, 1024, 0, stream>>>(scr + F_P1, d2, inp, ck, rec,
                                        scr + F_QTA, scr + F_RT, scr + F_QT,
                                        scr + F_ST, 0);
        k_scores<<<64, 256, 0, stream>>>(scr + F_QT, mem, scr + F_STAT,
                                         scr + F_PC);
        k_final<<<1, 256, 0, stream>>>(scr + F_RT, scr + F_ST, scr + F_STAT,
                                       scr + F_PC, mem, rec, px, py, out);
        k_transpose<<<dim3(64, 4), 256, 0, stream>>>(mem, px, py, out + 512);
    }
}

// Round 10
// 280.186 us; speedup vs baseline: 1.9285x; 1.1229x over previous
//
#include <hip/hip_runtime.h>

// NeuralMapCell — ROUND 25. R24 passed (314.6us). Theory: ~40us hidden in
// SERIALIZED staging loads (runtime trip counts -> compiler emits
// load/waitcnt/add serially at ~400cyc L3 latency). conv2's 8-chunk halo
// sum alone ~16us. Fix: explicit register-batched staging (loads issued
// together, adds in IDENTICAL order -> bit-identical results):
//   - conv2 halo: nchunks==8 compile-path, 8 named loads; outer unroll 2
//   - conv1: 9-load k-slice batch + 4-round mem-halo batch
//   - conv2 k2-stage: 5-round batch
//   - fused/final/scores GEMV unrolls 8->16 (order preserved)
// Structure/launches identical to R24 (6 kernels ws path).
//
// d_out = float[1049088]: c_t[256] r_t[256] new_mem[1048576].
// scr = out + 512; c1p[8][32][4096] fills scr, dead after K2 (ws path), so
// K3's transpose overwrites scr with the real new_mem (skips pxy column).
#define FLAT  238144      // 64*61*61
#define NB_R1 931

// ws float offsets (ws path)
#define W_C2   0          // 246016
#define W_P1   246016     // 119168 -> 365184
#define W_RT   365184     // 256
#define W_ST   365440     // 256
#define W_QT   365696     // 256
#define W_QTA  365952     // 256
#define W_STAT 366208     // 128 (64 x {max,expsum})
#define W_PC   366336     // 16384 (64 x 256) unnormalized partial PV
#define W_WARM 382720     // 16
#define W_END  382736

// scr float offsets (fallback path; transpose runs LAST, separately)
#define F_C2   140416
#define F_P1   386432     // -> 505600
#define F_RT   505600
#define F_ST   505856
#define F_QT   506112
#define F_QTA  506368
#define F_STAT 510464
#define F_PC   510592     // -> 526976

__device__ __forceinline__ int read_idx(const int* p) {
    unsigned int u = (unsigned int)*p;
    int ex = (int)((u >> 23) & 0xFF);
    int v;
    if (ex >= 118 && ex <= 140) {
        union { unsigned int i; float f; } c; c.i = u;
        v = (int)(c.f + 0.5f);
    } else {
        v = (int)u;
    }
    return v < 0 ? 0 : (v > 63 ? 63 : v);
}

// ---- K1: conv1 (cross-corr, SAME, 3x3, 256->32): c1p[chunk][o][4096]
__global__ __launch_bounds__(256) void k_conv1(const float* __restrict__ mem,
                                               const float* __restrict__ k1,
                                               float* __restrict__ c1p) {
    __shared__ float sm[32 * 105];
    __shared__ __align__(16) float sk[9 * 32 * 32];
    int t = threadIdx.x;
    int th = (blockIdx.x >> 3) * 8;
    int tw = (blockIdx.x & 7) * 8;
    int chunk = blockIdx.y;
    // mem halo: 800 units, batched 4 rounds (loads issued together)
    {
        float4 mv[4];
        #pragma unroll
        for (int k = 0; k < 4; ++k) {
            int u = t + k * 256;
            float4 v = make_float4(0.f, 0.f, 0.f, 0.f);
            if (u < 800) {
                int pix = u >> 3, c4 = u & 7;
                int hh = th - 1 + pix / 10;
                int ww = tw - 1 + pix % 10;
                if ((unsigned)hh < 64u && (unsigned)ww < 64u)
                    v = *(const float4*)(mem + (size_t)(hh * 64 + ww) * 256
                                             + chunk * 32 + c4 * 4);
            }
            mv[k] = v;
        }
        #pragma unroll
        for (int k = 0; k < 4; ++k) {
            int u = t + k * 256;
            if (u < 800) {
                int pix = u >> 3, c4 = u & 7;
                int ib = c4 * 4;
                sm[(ib    ) * 105 + pix] = mv[k].x;
                sm[(ib + 1) * 105 + pix] = mv[k].y;
                sm[(ib + 2) * 105 + pix] = mv[k].z;
                sm[(ib + 3) * 105 + pix] = mv[k].w;
            }
        }
    }
    // k-slice: exactly 9 rounds (tap=k, r=t) — 9 loads in flight
    {
        float4 kv[9];
        #pragma unroll
        for (int k = 0; k < 9; ++k)
            kv[k] = ((const float4*)(k1 + (size_t)k * 8192
                                        + (size_t)chunk * 1024))[t];
        #pragma unroll
        for (int k = 0; k < 9; ++k)
            *(float4*)&sk[k * 1024 + t * 4] = kv[k];
    }
    __syncthreads();
    int lh = (t & 63) >> 3, lw = t & 7, og = t >> 6;
    float acc[8];
    #pragma unroll
    for (int j = 0; j < 8; ++j) acc[j] = 0.f;
    for (int dh = 0; dh < 3; ++dh)
        for (int dw = 0; dw < 3; ++dw) {
            int pixb = (lh + dh) * 10 + (lw + dw);
            const float* kt = sk + (dh * 3 + dw) * 1024 + og * 8;
            #pragma unroll 4
            for (int i = 0; i < 32; ++i) {
                float m = sm[i * 105 + pixb];
                float4 ka = *(const float4*)(kt + i * 32);
                float4 kb = *(const float4*)(kt + i * 32 + 4);
                acc[0] += m * ka.x; acc[1] += m * ka.y;
                acc[2] += m * ka.z; acc[3] += m * ka.w;
                acc[4] += m * kb.x; acc[5] += m * kb.y;
                acc[6] += m * kb.z; acc[7] += m * kb.w;
            }
        }
    int p = (th + lh) * 64 + tw + lw;
    float* dst = c1p + (size_t)chunk * 131072 + (size_t)(og * 8) * 4096 + p;
    #pragma unroll
    for (int j = 0; j < 8; ++j)
        dst[(size_t)j * 4096] = acc[j];
}

// ---- fallback only: compact 8 chunk partials (ascending order)
__global__ __launch_bounds__(256) void k_c1red(float* __restrict__ c1p) {
    int idx = blockIdx.x * 256 + threadIdx.x;
    float s = 0.f;
    #pragma unroll
    for (int c = 0; c < 8; ++c) s += c1p[(size_t)c * 131072 + idx];
    c1p[idx] = s;
}

// ---- K2: conv2 (VALID, 3x3, 32->64); staging sums nchunks partials.
// nchunks==8 path: 8 loads issued together, adds in ascending-c order
// (bit-identical to the serial loop).
__global__ __launch_bounds__(256) void k_conv2(const float* __restrict__ c1p,
                                               const float* __restrict__ k2,
                                               float* __restrict__ c2,
                                               int nchunks) {
    __shared__ float sm[32 * 104];
    __shared__ __align__(16) float sk2[9 * 32 * 16];
    int t = threadIdx.x;
    int th = (blockIdx.x >> 3) * 8;
    int tw = (blockIdx.x & 7) * 8;
    int o0 = blockIdx.y * 16;
    if (nchunks == 8) {
        #pragma unroll 2
        for (int u = t; u < 3200; u += 256) {
            int i = u / 100;
            int pix = u % 100;
            int hh = th + pix / 10;
            int ww = tw + pix % 10;
            float v = 0.f;
            if (hh < 64 && ww < 64) {
                const float* p = c1p + (size_t)i * 4096 + hh * 64 + ww;
                float a0 = p[0];
                float a1 = p[131072];
                float a2 = p[2 * 131072];
                float a3 = p[3 * 131072];
                float a4 = p[4 * 131072];
                float a5 = p[5 * 131072];
                float a6 = p[6 * 131072];
                float a7 = p[7 * 131072];
                v = a0 + a1 + a2 + a3 + a4 + a5 + a6 + a7;
            }
            sm[i * 104 + pix] = v;
        }
    } else {
        for (int u = t; u < 3200; u += 256) {
            int i = u / 100;
            int pix = u % 100;
            int hh = th + pix / 10;
            int ww = tw + pix % 10;
            float v = 0.f;
            if (hh < 64 && ww < 64)
                v = c1p[(size_t)i * 4096 + hh * 64 + ww];
            sm[i * 104 + pix] = v;
        }
    }
    // k2 stage: 1152 units, batched 5 rounds
    {
        float4 kv[5];
        #pragma unroll
        for (int k = 0; k < 5; ++k) {
            int u = t + k * 256;
            if (u < 1152) {
                int tap = u >> 7, r = u & 127;
                int i = r >> 2, o4 = r & 3;
                kv[k] = *(const float4*)(k2 + (size_t)tap * 2048 + i * 64
                                            + o0 + o4 * 4);
            }
        }
        #pragma unroll
        for (int k = 0; k < 5; ++k) {
            int u = t + k * 256;
            if (u < 1152) {
                int tap = u >> 7, r = u & 127;
                int i = r >> 2, o4 = r & 3;
                *(float4*)&sk2[tap * 512 + i * 16 + o4 * 4] = kv[k];
            }
        }
    }
    __syncthreads();
    int pix = t & 63;
    int lh = pix >> 3, lw = pix & 7, og = t >> 6;
    float acc[4] = {0.f, 0.f, 0.f, 0.f};
    for (int dh = 0; dh < 3; ++dh)
        for (int dw = 0; dw < 3; ++dw) {
            int pixb = (lh + dh) * 10 + (lw + dw);
            const float* kt = sk2 + (dh * 3 + dw) * 512 + og * 4;
            #pragma unroll 8
            for (int i = 0; i < 32; ++i) {
                float m = sm[i * 104 + pixb];
                float4 kv = *(const float4*)(kt + i * 16);
                acc[0] += m * kv.x; acc[1] += m * kv.y;
                acc[2] += m * kv.z; acc[3] += m * kv.w;
            }
        }
    int h = th + lh, w = tw + lw;
    if (h < 62 && w < 62) {
        #pragma unroll
        for (int j = 0; j < 4; ++j)
            c2[(size_t)(o0 + og * 4 + j) * 3844 + h * 62 + w] = acc[j];
    }
}

// ---- K3: withx=1 (ws): [0..255]=transpose, [256..1186]=r1p,
//      [1187]=st, [1188]=qta, [1189..1202]=warm-stream d2/rec2/ck2.
//      withx=0 (fb): all blocks r1p.
__global__ __launch_bounds__(256) void k_r1pt(const float* __restrict__ c2,
                                              const float* __restrict__ d1,
                                              float* __restrict__ p1,
                                              const float* __restrict__ mem,
                                              const int* __restrict__ px,
                                              const int* __restrict__ py,
                                              float* __restrict__ outm,
                                              const float* __restrict__ d2,
                                              const float* __restrict__ ck,
                                              const float* __restrict__ rec,
                                              const float* __restrict__ inp,
                                              float* __restrict__ st,
                                              float* __restrict__ qta,
                                              float* __restrict__ warm,
                                              int withx) {
    __shared__ __align__(16) float SM[4160];
    int t = threadIdx.x;
    int bid = blockIdx.x;
    int fb = -1;
    if (!withx) {
        fb = bid;
    } else if (bid < 256) {
        // ---- transpose unit
        int tu = bid;
        float* tile = SM;            // [64][65]
        int p0 = (tu & 63) * 64;
        int u0 = (tu >> 6) * 64;
        int x = read_idx(px), y = read_idx(py);
        int pxy = x * 64 + y;
        int lane = t & 63, grp = t >> 6;
        for (int r = 0; r < 16; ++r) {
            int pr = grp + r * 4;
            tile[pr * 65 + lane] = mem[(size_t)(p0 + pr) * 256 + u0 + lane];
        }
        __syncthreads();
        for (int r = 0; r < 16; ++r) {
            int ur = grp + r * 4;
            if (p0 + lane != pxy)
                outm[(size_t)(u0 + ur) * 4096 + p0 + lane] = tile[lane * 65 + ur];
        }
        return;
    } else if (bid < 256 + NB_R1) {
        fb = bid - 256;
    } else if (bid == 256 + NB_R1) {
        // ---- st = inp @ rec[:128]  (bit-identical order)
        float sv = 0.f;
        #pragma unroll 16
        for (int k = 0; k < 128; ++k) sv += inp[k] * rec[k * 256 + t];
        st[t] = sv;
        return;
    } else if (bid == 257 + NB_R1) {
        // ---- qta = inp @ ck[:128]  (bit-identical prefix of qt)
        float q = 0.f;
        #pragma unroll 16
        for (int k = 0; k < 128; ++k) q += inp[k] * ck[k * 256 + t];
        qta[t] = q;
        return;
    } else {
        // ---- warm: d2 (f4 0..8191), rec rows 128..383, ck rows 128..383
        int wu = bid - (258 + NB_R1);      // 0..13
        float a = 0.f;
        for (int k = 0; k < 12; ++k) {
            int j = (wu * 256 + t) + k * 3584;
            if (j < 40960) {
                float4 v;
                if (j < 8192)        v = ((const float4*)d2 )[j];
                else if (j < 24576)  v = ((const float4*)rec)[j];
                else                 v = ((const float4*)ck )[j - 16384];
                a += v.x + v.y + v.z + v.w;
            }
        }
        SM[t] = a;
        __syncthreads();
        if (t == 0) {
            float s = 0.f;
            for (int i = 0; i < 256; ++i) s += SM[i];
            warm[wu] = s;
        }
        return;
    }
    // ---- r1p unit
    {
        float* pl   = SM;
        float* sred = SM + 256;
        int f0 = fb * 256;
        int fmax = FLAT - f0; if (fmax > 256) fmax = 256;
        for (int s = t; s < fmax; s += 256) {
            int f = f0 + s;
            int o = f / 3721;
            int r = f % 3721;
            int h = r / 61, w = r % 61;
            const float* b = c2 + (size_t)o * 3844 + h * 62 + w;
            pl[s] = 0.25f * (b[0] + b[1] + b[62] + b[63]);
        }
        __syncthreads();
        int jq = t & 31, g = t >> 5;
        float4 a = make_float4(0.f, 0.f, 0.f, 0.f);
        if (fmax == 256) {
            #pragma unroll 8
            for (int it = 0; it < 32; ++it) {
                int s = g + it * 8;
                float m = pl[s];
                float4 dv = *(const float4*)(d1 + (size_t)(f0 + s) * 128 + jq * 4);
                a.x += m * dv.x; a.y += m * dv.y; a.z += m * dv.z; a.w += m * dv.w;
            }
        } else {
            for (int s = g; s < fmax; s += 8) {
                float m = pl[s];
                float4 dv = *(const float4*)(d1 + (size_t)(f0 + s) * 128 + jq * 4);
                a.x += m * dv.x; a.y += m * dv.y; a.z += m * dv.z; a.w += m * dv.w;
            }
        }
        *(float4*)&sred[(g * 32 + jq) * 4] = a;
        __syncthreads();
        if (t < 32) {
            float4 s4 = make_float4(0.f, 0.f, 0.f, 0.f);
            #pragma unroll
            for (int gg = 0; gg < 8; ++gg) {
                float4 v = *(const float4*)&sred[(gg * 32 + t) * 4];
                s4.x += v.x; s4.y += v.y; s4.z += v.z; s4.w += v.w;
            }
            *(float4*)(p1 + (size_t)fb * 128 + t * 4) = s4;
        }
    }
}

// ---- K4: fused r1 reduce + rt + qt-tail. haveAux=1: st/qta precomputed.
__global__ __launch_bounds__(1024) void k_fused(const float* __restrict__ p1,
                                                const float* __restrict__ d2,
                                                const float* __restrict__ inp,
                                                const float* __restrict__ ck,
                                                const float* __restrict__ rec,
                                                const float* __restrict__ qta,
                                                float* __restrict__ rt,
                                                float* __restrict__ qt,
                                                float* __restrict__ st,
                                                int haveAux) {
    __shared__ float p2s[8][128];
    __shared__ float s_r1[128], s_in[128], s_rt[256];
    int t = threadIdx.x;
    int j = t & 127, part = t >> 7;
    int b0 = part * 117;
    int b1 = b0 + 117; if (b1 > NB_R1) b1 = NB_R1;
    float s = 0.f;
    #pragma unroll 8
    for (int b = b0; b < b1; ++b) s += p1[b * 128 + j];
    p2s[part][j] = s;
    if (t < 128) s_in[t] = inp[t];
    __syncthreads();
    if (t < 128) {
        float r = 0.f;
        #pragma unroll
        for (int c = 0; c < 8; ++c) r += p2s[c][t];
        s_r1[t] = r;
    }
    __syncthreads();
    if (t < 256) {
        float a = 0.f;
        #pragma unroll 16
        for (int k = 0; k < 128; ++k) a += s_r1[k] * d2[k * 256 + t];
        rt[t] = a; s_rt[t] = a;
        if (!haveAux) {
            float sv = 0.f;
            #pragma unroll 16
            for (int k = 0; k < 128; ++k) sv += s_in[k] * rec[k * 256 + t];
            st[t] = sv;
        }
    }
    __syncthreads();
    if (t < 256) {
        float q;
        if (haveAux) {
            q = qta[t];
        } else {
            q = 0.f;
            #pragma unroll 16
            for (int k = 0; k < 128; ++k) q += s_in[k] * ck[k * 256 + t];
        }
        #pragma unroll 16
        for (int k = 0; k < 256; ++k) q += s_rt[k] * ck[(128 + k) * 256 + t];
        qt[t] = q;
    }
}

// ---- K5: scores + stats + UNNORMALIZED partial PV (64 blocks, 64 rows each)
__global__ __launch_bounds__(256) void k_scores(const float* __restrict__ qt,
                                                const float* __restrict__ mem,
                                                float* __restrict__ stat,
                                                float* __restrict__ pc) {
    __shared__ float q[256];
    __shared__ float rowv[64], aL[64];
    __shared__ float mbS;
    int t = threadIdx.x;
    int bid = blockIdx.x;
    q[t] = qt[t];
    __syncthreads();
    int wave = t >> 6, lane = t & 63;
    float qx = q[lane * 4], qy = q[lane * 4 + 1],
          qz = q[lane * 4 + 2], qw = q[lane * 4 + 3];
    int p0 = bid * 64;
    for (int r = 0; r < 16; ++r) {
        int p = p0 + wave * 16 + r;
        float4 m = *(const float4*)(mem + (size_t)p * 256 + lane * 4);
        float acc = m.x * qx + m.y * qy + m.z * qz + m.w * qw;
        for (int off = 32; off; off >>= 1) acc += __shfl_down(acc, off);
        if (lane == 0) rowv[wave * 16 + r] = acc;
    }
    __syncthreads();
    if (t == 0) {
        float mb = rowv[0];
        for (int i = 1; i < 64; ++i) mb = fmaxf(mb, rowv[i]);
        mbS = mb;
    }
    __syncthreads();
    if (t < 64) aL[t] = expf(rowv[t] - mbS);
    __syncthreads();
    if (t == 0) {
        float sb = 0.f;
        for (int i = 0; i < 64; ++i) sb += aL[i];
        stat[bid * 2]     = mbS;
        stat[bid * 2 + 1] = sb;
    }
    // unnormalized partial PV over this block's 64 rows (mem L1/L2-hot)
    float acc = 0.f;
    #pragma unroll 16
    for (int pp = 0; pp < 64; ++pp)
        acc += aL[pp] * mem[(size_t)(p0 + pp) * 256 + t];
    pc[bid * 256 + t] = acc;
}

// ---- K6: final (1 block; global softmax rescale + ct + mem update)
__global__ __launch_bounds__(256) void k_final(const float* __restrict__ rt,
                                               const float* __restrict__ st,
                                               const float* __restrict__ stat,
                                               const float* __restrict__ pc,
                                               const float* __restrict__ mem,
                                               const float* __restrict__ rec,
                                               const int* __restrict__ px,
                                               const int* __restrict__ py,
                                               float* __restrict__ out) {
    __shared__ float s_diff[256], red[256];
    __shared__ float sm_[64], wb[64], aux[2];
    int t = threadIdx.x;
    int x = read_idx(px), y = read_idx(py);
    int pxy = x * 64 + y;
    if (t < 64) sm_[t] = stat[t * 2];
    __syncthreads();
    if (t == 0) {
        float M = sm_[0];
        for (int i = 1; i < 64; ++i) M = fmaxf(M, sm_[i]);
        float S = 0.f;
        for (int i = 0; i < 64; ++i) S += stat[i * 2 + 1] * expf(sm_[i] - M);
        aux[0] = M; aux[1] = 1.f / S;
    }
    __syncthreads();
    if (t < 64) wb[t] = expf(sm_[t] - aux[0]) * aux[1];
    __syncthreads();
    float ctv = 0.f;
    #pragma unroll 16
    for (int b = 0; b < 64; ++b) ctv += pc[b * 256 + t] * wb[b];
    float stv = st[t], rtv = rt[t];
    float memt = mem[(size_t)pxy * 256 + t];
    red[t] = stv * rtv; __syncthreads();
    for (int s = 128; s; s >>= 1) { if (t < s) red[t] += red[t + s]; __syncthreads(); }
    float gimp = red[0]; __syncthreads();
    red[t] = stv * ctv; __syncthreads();
    for (int s = 128; s; s >>= 1) { if (t < s) red[t] += red[t + s]; __syncthreads(); }
    float limp = red[0];
    s_diff[t] = memt - stv;
    __syncthreads();
    float d = 0.f;
    #pragma unroll 16
    for (int k = 0; k < 256; ++k)
        d += s_diff[k] * rec[(128 + k) * 256 + t];
    float frac = limp / (limp + gimp);
    out[t] = ctv;
    out[256 + t] = rtv;
    out[512 + (size_t)t * 4096 + pxy] = memt + frac * d;
}

// ---- fallback only: standalone transpose (runs LAST on scr path)
__global__ __launch_bounds__(256) void k_transpose(const float* __restrict__ mem,
                                                   const int* __restrict__ px,
                                                   const int* __restrict__ py,
                                                   float* __restrict__ outm) {
    __shared__ float tile[64][65];
    int t = threadIdx.x;
    int p0 = blockIdx.x * 64;
    int u0 = blockIdx.y * 64;
    int x = read_idx(px), y = read_idx(py);
    int pxy = x * 64 + y;
    int lane = t & 63, grp = t >> 6;
    for (int r = 0; r < 16; ++r) {
        int pr = grp + r * 4;
        tile[pr][lane] = mem[(size_t)(p0 + pr) * 256 + u0 + lane];
    }
    __syncthreads();
    for (int r = 0; r < 16; ++r) {
        int ur = grp + r * 4;
        if (p0 + lane != pxy)
            outm[(size_t)(u0 + ur) * 4096 + p0 + lane] = tile[lane][ur];
    }
}

extern "C" void kernel_launch(void* const* d_in, const int* in_sizes, int n_in,
                              void* d_out, int out_size, void* d_ws, size_t ws_size,
                              hipStream_t stream) {
    const float* inp = (const float*)d_in[0];
    const float* mem = (const float*)d_in[1];
    const float* k1  = (const float*)d_in[2];
    const float* k2  = (const float*)d_in[3];
    const float* d1  = (const float*)d_in[4];
    const float* d2  = (const float*)d_in[5];
    const float* ck  = (const float*)d_in[6];
    const float* rec = (const float*)d_in[7];
    const int* px = (const int*)d_in[8];
    const int* py = (const int*)d_in[9];
    float* out = (float*)d_out;
    float* scr = out + 512;
    float* ws  = (float*)d_ws;

    bool useWs = (ws != nullptr) && (ws_size >= (size_t)W_END * sizeof(float));

    if (useWs) {
        k_conv1<<<dim3(64, 8), 256, 0, stream>>>(mem, k1, scr);
        k_conv2<<<dim3(64, 4), 256, 0, stream>>>(scr, k2, ws + W_C2, 8);
        k_r1pt<<<256 + NB_R1 + 16, 256, 0, stream>>>(
            ws + W_C2, d1, ws + W_P1, mem, px, py, scr,
            d2, ck, rec, inp, ws + W_ST, ws + W_QTA, ws + W_WARM, 1);
        k_fused<<<1, 1024, 0, stream>>>(ws + W_P1, d2, inp, ck, rec,
                                        ws + W_QTA, ws + W_RT, ws + W_QT,
                                        ws + W_ST, 1);
        k_scores<<<64, 256, 0, stream>>>(ws + W_QT, mem, ws + W_STAT,
                                         ws + W_PC);
        k_final<<<1, 256, 0, stream>>>(ws + W_RT, ws + W_ST, ws + W_STAT,
                                       ws + W_PC, mem, rec, px, py, out);
    } else {
        k_conv1<<<dim3(64, 8), 256, 0, stream>>>(mem, k1, scr);
        k_c1red<<<512, 256, 0, stream>>>(scr);
        k_conv2<<<dim3(64, 4), 256, 0, stream>>>(scr, k2, scr + F_C2, 1);
        k_r1pt<<<NB_R1, 256, 0, stream>>>(
            scr + F_C2, d1, scr + F_P1, mem, px, py, scr,
            d2, ck, rec, inp, scr + F_ST, scr + F_QTA, scr + F_PC + 16384, 0);
        k_fused<<<1, 1024, 0, stream>>>(scr + F_P1, d2, inp, ck, rec,
                                        scr + F_QTA, scr + F_RT, scr + F_QT,
                                        scr + F_ST, 0);
        k_scores<<<64, 256, 0, stream>>>(scr + F_QT, mem, scr + F_STAT,
                                         scr + F_PC);
        k_final<<<1, 256, 0, stream>>>(scr + F_RT, scr + F_ST, scr + F_STAT,
                                       scr + F_PC, mem, rec, px, py, out);
        k_transpose<<<dim3(64, 4), 256, 0, stream>>>(mem, px, py, out + 512);
    }
}

// Round 11
// 277.974 us; speedup vs baseline: 1.9438x; 1.0080x over previous
//
#include <hip/hip_runtime.h>

// NeuralMapCell — ROUND 26. R25 passed 280.2us (-34; batched-staging theory
// confirmed). Controllable chain ~103us vs ~87us floor. R26: (1) c1p moved
// to ws -> scr free at t=0 -> transpose/st/qta/warm become EXTRA BLOCKS of
// the conv1 launch (k_front, 784 blocks; they depend on nothing conv1
// makes); k_r1p is now a pure 931-block d1 stream. (2) r1p unroll 8->16.
// Still 6 launches, no new sync patterns, all math bit-identical to R25.
//
// d_out = float[1049088]: c_t[256] r_t[256] new_mem[1048576].
// scr = out + 512: transpose fills new_mem during K1 (skips pxy column,
// which k_final writes). c1p lives in ws (W_C1P).
#define FLAT  238144      // 64*61*61
#define NB_R1 931

// ws float offsets (ws path)
#define W_C2   0          // 246016
#define W_P1   246016     // 119168 -> 365184
#define W_RT   365184     // 256
#define W_ST   365440     // 256
#define W_QT   365696     // 256
#define W_QTA  365952     // 256
#define W_STAT 366208     // 128 (64 x {max,expsum})
#define W_PC   366336     // 16384 (64 x 256) unnormalized partial PV
#define W_WARM 382720     // 16
#define W_C1P  382736     // 1048576 conv1 chunk partials [8][32][4096]
#define W_END  1431312

// scr float offsets (fallback path; transpose runs LAST, separately)
#define F_C2   140416
#define F_P1   386432     // -> 505600
#define F_RT   505600
#define F_ST   505856
#define F_QT   506112
#define F_QTA  506368
#define F_STAT 510464
#define F_PC   510592     // -> 526976

__device__ __forceinline__ int read_idx(const int* p) {
    unsigned int u = (unsigned int)*p;
    int ex = (int)((u >> 23) & 0xFF);
    int v;
    if (ex >= 118 && ex <= 140) {
        union { unsigned int i; float f; } c; c.i = u;
        v = (int)(c.f + 0.5f);
    } else {
        v = (int)u;
    }
    return v < 0 ? 0 : (v > 63 ? 63 : v);
}

// ---- K1 "front": mode 1 (ws): [0..511]=conv1, [512..767]=transpose,
//      [768]=st, [769]=qta, [770..783]=warm. mode 0 (fb): all conv1.
__global__ __launch_bounds__(256) void k_front(const float* __restrict__ mem,
                                               const float* __restrict__ k1,
                                               float* __restrict__ c1p,
                                               const int* __restrict__ px,
                                               const int* __restrict__ py,
                                               float* __restrict__ outm,
                                               const float* __restrict__ inp,
                                               const float* __restrict__ rec,
                                               const float* __restrict__ ck,
                                               const float* __restrict__ d2,
                                               float* __restrict__ st,
                                               float* __restrict__ qta,
                                               float* __restrict__ warm,
                                               int mode) {
    __shared__ __align__(16) float SM[12576];   // conv1: sm(3360)+sk(9216)
    int t = threadIdx.x;
    int bid = blockIdx.x;
    if (mode == 1 && bid >= 512) {
        if (bid < 768) {
            // ---- transpose unit: new_mem[u][p] = mem[p][u], skip pxy col
            int tu = bid - 512;
            float* tile = SM;                   // [64][65]
            int p0 = (tu & 63) * 64;
            int u0 = (tu >> 6) * 64;
            int x = read_idx(px), y = read_idx(py);
            int pxy = x * 64 + y;
            int lane = t & 63, grp = t >> 6;
            for (int r = 0; r < 16; ++r) {
                int pr = grp + r * 4;
                tile[pr * 65 + lane] = mem[(size_t)(p0 + pr) * 256 + u0 + lane];
            }
            __syncthreads();
            for (int r = 0; r < 16; ++r) {
                int ur = grp + r * 4;
                if (p0 + lane != pxy)
                    outm[(size_t)(u0 + ur) * 4096 + p0 + lane] =
                        tile[lane * 65 + ur];
            }
        } else if (bid == 768) {
            // ---- st = inp @ rec[:128] (bit-identical order)
            float sv = 0.f;
            #pragma unroll 16
            for (int k = 0; k < 128; ++k) sv += inp[k] * rec[k * 256 + t];
            st[t] = sv;
        } else if (bid == 769) {
            // ---- qta = inp @ ck[:128] (bit-identical prefix of qt)
            float q = 0.f;
            #pragma unroll 16
            for (int k = 0; k < 128; ++k) q += inp[k] * ck[k * 256 + t];
            qta[t] = q;
        } else {
            // ---- warm: d2 f4[0..8191], rec f4[8192..24575], ck f4 rows 128+
            int wu = bid - 770;                 // 0..13
            float a = 0.f;
            for (int k = 0; k < 12; ++k) {
                int j = (wu * 256 + t) + k * 3584;
                if (j < 40960) {
                    float4 v;
                    if (j < 8192)        v = ((const float4*)d2 )[j];
                    else if (j < 24576)  v = ((const float4*)rec)[j];
                    else                 v = ((const float4*)ck )[j - 16384];
                    a += v.x + v.y + v.z + v.w;
                }
            }
            SM[t] = a;
            __syncthreads();
            if (t == 0) {
                float s = 0.f;
                for (int i = 0; i < 256; ++i) s += SM[i];
                warm[wu] = s;
            }
        }
        return;
    }
    // ---- conv1 unit (cross-corr, SAME, 3x3, 256->32): c1p[chunk][o][4096]
    float* sm = SM;                 // [32][105]
    float* sk = SM + 3360;          // [9][32][32]
    int th = ((bid & 63) >> 3) * 8;
    int tw = (bid & 7) * 8;
    int chunk = bid >> 6;
    {
        float4 mv[4];
        #pragma unroll
        for (int k = 0; k < 4; ++k) {
            int u = t + k * 256;
            float4 v = make_float4(0.f, 0.f, 0.f, 0.f);
            if (u < 800) {
                int pix = u >> 3, c4 = u & 7;
                int hh = th - 1 + pix / 10;
                int ww = tw - 1 + pix % 10;
                if ((unsigned)hh < 64u && (unsigned)ww < 64u)
                    v = *(const float4*)(mem + (size_t)(hh * 64 + ww) * 256
                                             + chunk * 32 + c4 * 4);
            }
            mv[k] = v;
        }
        #pragma unroll
        for (int k = 0; k < 4; ++k) {
            int u = t + k * 256;
            if (u < 800) {
                int pix = u >> 3, c4 = u & 7;
                int ib = c4 * 4;
                sm[(ib    ) * 105 + pix] = mv[k].x;
                sm[(ib + 1) * 105 + pix] = mv[k].y;
                sm[(ib + 2) * 105 + pix] = mv[k].z;
                sm[(ib + 3) * 105 + pix] = mv[k].w;
            }
        }
    }
    {
        float4 kv[9];
        #pragma unroll
        for (int k = 0; k < 9; ++k)
            kv[k] = ((const float4*)(k1 + (size_t)k * 8192
                                        + (size_t)chunk * 1024))[t];
        #pragma unroll
        for (int k = 0; k < 9; ++k)
            *(float4*)&sk[k * 1024 + t * 4] = kv[k];
    }
    __syncthreads();
    int lh = (t & 63) >> 3, lw = t & 7, og = t >> 6;
    float acc[8];
    #pragma unroll
    for (int j = 0; j < 8; ++j) acc[j] = 0.f;
    for (int dh = 0; dh < 3; ++dh)
        for (int dw = 0; dw < 3; ++dw) {
            int pixb = (lh + dh) * 10 + (lw + dw);
            const float* kt = sk + (dh * 3 + dw) * 1024 + og * 8;
            #pragma unroll 4
            for (int i = 0; i < 32; ++i) {
                float m = sm[i * 105 + pixb];
                float4 ka = *(const float4*)(kt + i * 32);
                float4 kb = *(const float4*)(kt + i * 32 + 4);
                acc[0] += m * ka.x; acc[1] += m * ka.y;
                acc[2] += m * ka.z; acc[3] += m * ka.w;
                acc[4] += m * kb.x; acc[5] += m * kb.y;
                acc[6] += m * kb.z; acc[7] += m * kb.w;
            }
        }
    int p = (th + lh) * 64 + tw + lw;
    float* dst = c1p + (size_t)chunk * 131072 + (size_t)(og * 8) * 4096 + p;
    #pragma unroll
    for (int j = 0; j < 8; ++j)
        dst[(size_t)j * 4096] = acc[j];
}

// ---- fallback only: compact 8 chunk partials (ascending order)
__global__ __launch_bounds__(256) void k_c1red(float* __restrict__ c1p) {
    int idx = blockIdx.x * 256 + threadIdx.x;
    float s = 0.f;
    #pragma unroll
    for (int c = 0; c < 8; ++c) s += c1p[(size_t)c * 131072 + idx];
    c1p[idx] = s;
}

// ---- K2: conv2 (VALID, 3x3, 32->64); staging sums nchunks partials
__global__ __launch_bounds__(256) void k_conv2(const float* __restrict__ c1p,
                                               const float* __restrict__ k2,
                                               float* __restrict__ c2,
                                               int nchunks) {
    __shared__ float sm[32 * 104];
    __shared__ __align__(16) float sk2[9 * 32 * 16];
    int t = threadIdx.x;
    int th = (blockIdx.x >> 3) * 8;
    int tw = (blockIdx.x & 7) * 8;
    int o0 = blockIdx.y * 16;
    if (nchunks == 8) {
        #pragma unroll 2
        for (int u = t; u < 3200; u += 256) {
            int i = u / 100;
            int pix = u % 100;
            int hh = th + pix / 10;
            int ww = tw + pix % 10;
            float v = 0.f;
            if (hh < 64 && ww < 64) {
                const float* p = c1p + (size_t)i * 4096 + hh * 64 + ww;
                float a0 = p[0];
                float a1 = p[131072];
                float a2 = p[2 * 131072];
                float a3 = p[3 * 131072];
                float a4 = p[4 * 131072];
                float a5 = p[5 * 131072];
                float a6 = p[6 * 131072];
                float a7 = p[7 * 131072];
                v = a0 + a1 + a2 + a3 + a4 + a5 + a6 + a7;
            }
            sm[i * 104 + pix] = v;
        }
    } else {
        for (int u = t; u < 3200; u += 256) {
            int i = u / 100;
            int pix = u % 100;
            int hh = th + pix / 10;
            int ww = tw + pix % 10;
            float v = 0.f;
            if (hh < 64 && ww < 64)
                v = c1p[(size_t)i * 4096 + hh * 64 + ww];
            sm[i * 104 + pix] = v;
        }
    }
    {
        float4 kv[5];
        #pragma unroll
        for (int k = 0; k < 5; ++k) {
            int u = t + k * 256;
            if (u < 1152) {
                int tap = u >> 7, r = u & 127;
                int i = r >> 2, o4 = r & 3;
                kv[k] = *(const float4*)(k2 + (size_t)tap * 2048 + i * 64
                                            + o0 + o4 * 4);
            }
        }
        #pragma unroll
        for (int k = 0; k < 5; ++k) {
            int u = t + k * 256;
            if (u < 1152) {
                int tap = u >> 7, r = u & 127;
                int i = r >> 2, o4 = r & 3;
                *(float4*)&sk2[tap * 512 + i * 16 + o4 * 4] = kv[k];
            }
        }
    }
    __syncthreads();
    int pix = t & 63;
    int lh = pix >> 3, lw = pix & 7, og = t >> 6;
    float acc[4] = {0.f, 0.f, 0.f, 0.f};
    for (int dh = 0; dh < 3; ++dh)
        for (int dw = 0; dw < 3; ++dw) {
            int pixb = (lh + dh) * 10 + (lw + dw);
            const float* kt = sk2 + (dh * 3 + dw) * 512 + og * 4;
            #pragma unroll 8
            for (int i = 0; i < 32; ++i) {
                float m = sm[i * 104 + pixb];
                float4 kv = *(const float4*)(kt + i * 16);
                acc[0] += m * kv.x; acc[1] += m * kv.y;
                acc[2] += m * kv.z; acc[3] += m * kv.w;
            }
        }
    int h = th + lh, w = tw + lw;
    if (h < 62 && w < 62) {
        #pragma unroll
        for (int j = 0; j < 4; ++j)
            c2[(size_t)(o0 + og * 4 + j) * 3844 + h * 62 + w] = acc[j];
    }
}

// ---- K3: pure r1p (931 blocks): pool + dense1 partials
__global__ __launch_bounds__(256) void k_r1p(const float* __restrict__ c2,
                                             const float* __restrict__ d1,
                                             float* __restrict__ p1) {
    __shared__ __align__(16) float SM[4160];
    int t = threadIdx.x;
    int fb = blockIdx.x;
    float* pl   = SM;
    float* sred = SM + 256;
    int f0 = fb * 256;
    int fmax = FLAT - f0; if (fmax > 256) fmax = 256;
    for (int s = t; s < fmax; s += 256) {
        int f = f0 + s;
        int o = f / 3721;
        int r = f % 3721;
        int h = r / 61, w = r % 61;
        const float* b = c2 + (size_t)o * 3844 + h * 62 + w;
        pl[s] = 0.25f * (b[0] + b[1] + b[62] + b[63]);
    }
    __syncthreads();
    int jq = t & 31, g = t >> 5;
    float4 a = make_float4(0.f, 0.f, 0.f, 0.f);
    if (fmax == 256) {
        #pragma unroll 16
        for (int it = 0; it < 32; ++it) {
            int s = g + it * 8;
            float m = pl[s];
            float4 dv = *(const float4*)(d1 + (size_t)(f0 + s) * 128 + jq * 4);
            a.x += m * dv.x; a.y += m * dv.y; a.z += m * dv.z; a.w += m * dv.w;
        }
    } else {
        for (int s = g; s < fmax; s += 8) {
            float m = pl[s];
            float4 dv = *(const float4*)(d1 + (size_t)(f0 + s) * 128 + jq * 4);
            a.x += m * dv.x; a.y += m * dv.y; a.z += m * dv.z; a.w += m * dv.w;
        }
    }
    *(float4*)&sred[(g * 32 + jq) * 4] = a;
    __syncthreads();
    if (t < 32) {
        float4 s4 = make_float4(0.f, 0.f, 0.f, 0.f);
        #pragma unroll
        for (int gg = 0; gg < 8; ++gg) {
            float4 v = *(const float4*)&sred[(gg * 32 + t) * 4];
            s4.x += v.x; s4.y += v.y; s4.z += v.z; s4.w += v.w;
        }
        *(float4*)(p1 + (size_t)fb * 128 + t * 4) = s4;
    }
}

// ---- K4: fused r1 reduce + rt + qt-tail. haveAux=1: st/qta precomputed.
__global__ __launch_bounds__(1024) void k_fused(const float* __restrict__ p1,
                                                const float* __restrict__ d2,
                                                const float* __restrict__ inp,
                                                const float* __restrict__ ck,
                                                const float* __restrict__ rec,
                                                const float* __restrict__ qta,
                                                float* __restrict__ rt,
                                                float* __restrict__ qt,
                                                float* __restrict__ st,
                                                int haveAux) {
    __shared__ float p2s[8][128];
    __shared__ float s_r1[128], s_in[128], s_rt[256];
    int t = threadIdx.x;
    int j = t & 127, part = t >> 7;
    int b0 = part * 117;
    int b1 = b0 + 117; if (b1 > NB_R1) b1 = NB_R1;
    float s = 0.f;
    #pragma unroll 8
    for (int b = b0; b < b1; ++b) s += p1[b * 128 + j];
    p2s[part][j] = s;
    if (t < 128) s_in[t] = inp[t];
    __syncthreads();
    if (t < 128) {
        float r = 0.f;
        #pragma unroll
        for (int c = 0; c < 8; ++c) r += p2s[c][t];
        s_r1[t] = r;
    }
    __syncthreads();
    if (t < 256) {
        float a = 0.f;
        #pragma unroll 16
        for (int k = 0; k < 128; ++k) a += s_r1[k] * d2[k * 256 + t];
        rt[t] = a; s_rt[t] = a;
        if (!haveAux) {
            float sv = 0.f;
            #pragma unroll 16
            for (int k = 0; k < 128; ++k) sv += s_in[k] * rec[k * 256 + t];
            st[t] = sv;
        }
    }
    __syncthreads();
    if (t < 256) {
        float q;
        if (haveAux) {
            q = qta[t];
        } else {
            q = 0.f;
            #pragma unroll 16
            for (int k = 0; k < 128; ++k) q += s_in[k] * ck[k * 256 + t];
        }
        #pragma unroll 16
        for (int k = 0; k < 256; ++k) q += s_rt[k] * ck[(128 + k) * 256 + t];
        qt[t] = q;
    }
}

// ---- K5: scores + stats + UNNORMALIZED partial PV (64 blocks, 64 rows each)
__global__ __launch_bounds__(256) void k_scores(const float* __restrict__ qt,
                                                const float* __restrict__ mem,
                                                float* __restrict__ stat,
                                                float* __restrict__ pc) {
    __shared__ float q[256];
    __shared__ float rowv[64], aL[64];
    __shared__ float mbS;
    int t = threadIdx.x;
    int bid = blockIdx.x;
    q[t] = qt[t];
    __syncthreads();
    int wave = t >> 6, lane = t & 63;
    float qx = q[lane * 4], qy = q[lane * 4 + 1],
          qz = q[lane * 4 + 2], qw = q[lane * 4 + 3];
    int p0 = bid * 64;
    for (int r = 0; r < 16; ++r) {
        int p = p0 + wave * 16 + r;
        float4 m = *(const float4*)(mem + (size_t)p * 256 + lane * 4);
        float acc = m.x * qx + m.y * qy + m.z * qz + m.w * qw;
        for (int off = 32; off; off >>= 1) acc += __shfl_down(acc, off);
        if (lane == 0) rowv[wave * 16 + r] = acc;
    }
    __syncthreads();
    if (t == 0) {
        float mb = rowv[0];
        for (int i = 1; i < 64; ++i) mb = fmaxf(mb, rowv[i]);
        mbS = mb;
    }
    __syncthreads();
    if (t < 64) aL[t] = expf(rowv[t] - mbS);
    __syncthreads();
    if (t == 0) {
        float sb = 0.f;
        for (int i = 0; i < 64; ++i) sb += aL[i];
        stat[bid * 2]     = mbS;
        stat[bid * 2 + 1] = sb;
    }
    float acc = 0.f;
    #pragma unroll 16
    for (int pp = 0; pp < 64; ++pp)
        acc += aL[pp] * mem[(size_t)(p0 + pp) * 256 + t];
    pc[bid * 256 + t] = acc;
}

// ---- K6: final (1 block; global softmax rescale + ct + mem update)
__global__ __launch_bounds__(256) void k_final(const float* __restrict__ rt,
                                               const float* __restrict__ st,
                                               const float* __restrict__ stat,
                                               const float* __restrict__ pc,
                                               const float* __restrict__ mem,
                                               const float* __restrict__ rec,
                                               const int* __restrict__ px,
                                               const int* __restrict__ py,
                                               float* __restrict__ out) {
    __shared__ float s_diff[256], red[256];
    __shared__ float sm_[64], wb[64], aux[2];
    int t = threadIdx.x;
    int x = read_idx(px), y = read_idx(py);
    int pxy = x * 64 + y;
    if (t < 64) sm_[t] = stat[t * 2];
    __syncthreads();
    if (t == 0) {
        float M = sm_[0];
        for (int i = 1; i < 64; ++i) M = fmaxf(M, sm_[i]);
        float S = 0.f;
        for (int i = 0; i < 64; ++i) S += stat[i * 2 + 1] * expf(sm_[i] - M);
        aux[0] = M; aux[1] = 1.f / S;
    }
    __syncthreads();
    if (t < 64) wb[t] = expf(sm_[t] - aux[0]) * aux[1];
    __syncthreads();
    float ctv = 0.f;
    #pragma unroll 16
    for (int b = 0; b < 64; ++b) ctv += pc[b * 256 + t] * wb[b];
    float stv = st[t], rtv = rt[t];
    float memt = mem[(size_t)pxy * 256 + t];
    red[t] = stv * rtv; __syncthreads();
    for (int s = 128; s; s >>= 1) { if (t < s) red[t] += red[t + s]; __syncthreads(); }
    float gimp = red[0]; __syncthreads();
    red[t] = stv * ctv; __syncthreads();
    for (int s = 128; s; s >>= 1) { if (t < s) red[t] += red[t + s]; __syncthreads(); }
    float limp = red[0];
    s_diff[t] = memt - stv;
    __syncthreads();
    float d = 0.f;
    #pragma unroll 16
    for (int k = 0; k < 256; ++k)
        d += s_diff[k] * rec[(128 + k) * 256 + t];
    float frac = limp / (limp + gimp);
    out[t] = ctv;
    out[256 + t] = rtv;
    out[512 + (size_t)t * 4096 + pxy] = memt + frac * d;
}

// ---- fallback only: standalone transpose (runs LAST on scr path)
__global__ __launch_bounds__(256) void k_transpose(const float* __restrict__ mem,
                                                   const int* __restrict__ px,
                                                   const int* __restrict__ py,
                                                   float* __restrict__ outm) {
    __shared__ float tile[64][65];
    int t = threadIdx.x;
    int p0 = blockIdx.x * 64;
    int u0 = blockIdx.y * 64;
    int x = read_idx(px), y = read_idx(py);
    int pxy = x * 64 + y;
    int lane = t & 63, grp = t >> 6;
    for (int r = 0; r < 16; ++r) {
        int pr = grp + r * 4;
        tile[pr][lane] = mem[(size_t)(p0 + pr) * 256 + u0 + lane];
    }
    __syncthreads();
    for (int r = 0; r < 16; ++r) {
        int ur = grp + r * 4;
        if (p0 + lane != pxy)
            outm[(size_t)(u0 + ur) * 4096 + p0 + lane] = tile[lane][ur];
    }
}

extern "C" void kernel_launch(void* const* d_in, const int* in_sizes, int n_in,
                              void* d_out, int out_size, void* d_ws, size_t ws_size,
                              hipStream_t stream) {
    const float* inp = (const float*)d_in[0];
    const float* mem = (const float*)d_in[1];
    const float* k1  = (const float*)d_in[2];
    const float* k2  = (const float*)d_in[3];
    const float* d1  = (const float*)d_in[4];
    const float* d2  = (const float*)d_in[5];
    const float* ck  = (const float*)d_in[6];
    const float* rec = (const float*)d_in[7];
    const int* px = (const int*)d_in[8];
    const int* py = (const int*)d_in[9];
    float* out = (float*)d_out;
    float* scr = out + 512;
    float* ws  = (float*)d_ws;

    bool useWs = (ws != nullptr) && (ws_size >= (size_t)W_END * sizeof(float));

    if (useWs) {
        k_front<<<784, 256, 0, stream>>>(mem, k1, ws + W_C1P, px, py, scr,
                                         inp, rec, ck, d2,
                                         ws + W_ST, ws + W_QTA, ws + W_WARM, 1);
        k_conv2<<<dim3(64, 4), 256, 0, stream>>>(ws + W_C1P, k2, ws + W_C2, 8);
        k_r1p<<<NB_R1, 256, 0, stream>>>(ws + W_C2, d1, ws + W_P1);
        k_fused<<<1, 1024, 0, stream>>>(ws + W_P1, d2, inp, ck, rec,
                                        ws + W_QTA, ws + W_RT, ws + W_QT,
                                        ws + W_ST, 1);
        k_scores<<<64, 256, 0, stream>>>(ws + W_QT, mem, ws + W_STAT,
                                         ws + W_PC);
        k_final<<<1, 256, 0, stream>>>(ws + W_RT, ws + W_ST, ws + W_STAT,
                                       ws + W_PC, mem, rec, px, py, out);
    } else {
        k_front<<<512, 256, 0, stream>>>(mem, k1, scr, px, py, scr,
                                         inp, rec, ck, d2,
                                         scr + F_ST, scr + F_QTA,
                                         scr + F_PC + 16384, 0);
        k_c1red<<<512, 256, 0, stream>>>(scr);
        k_conv2<<<dim3(64, 4), 256, 0, stream>>>(scr, k2, scr + F_C2, 1);
        k_r1p<<<NB_R1, 256, 0, stream>>>(scr + F_C2, d1, scr + F_P1);
        k_fused<<<1, 1024, 0, stream>>>(scr + F_P1, d2, inp, ck, rec,
                                        scr + F_QTA, scr + F_RT, scr + F_QT,
                                        scr + F_ST, 0);
        k_scores<<<64, 256, 0, stream>>>(scr + F_QT, mem, scr + F_STAT,
                                         scr + F_PC);
        k_final<<<1, 256, 0, stream>>>(scr + F_RT, scr + F_ST, scr + F_STAT,
                                       scr + F_PC, mem, rec, px, py, out);
        k_transpose<<<dim3(64, 4), 256, 0, stream>>>(mem, px, py, out + 512);
    }
}

// Round 12
// 272.701 us; speedup vs baseline: 1.9814x; 1.0193x over previous
//
#include <hip/hip_runtime.h>

// NeuralMapCell — ROUND 27. R26 neutral (-2.2us) -> chain ~101us vs ~85
// floor. R27, two last arithmetic-backed levers: (1) d1 L3-prefetch under
// conv2's shadow (127 blocks stream first ~50MB of d1, 8-deep batched;
// HBM idle during conv2) -> r1p's HBM-bound stream partially L3-hits.
// (2) k_final's 256-deep rec-GEMV hoisted to a conv2 extra block
// (d = (mem[:,pxy]-st)@rec[128:], bit-identical loop; st ready after
// k_front) -> 1-block tail shortens. If <=3us total: declare roofline.
//
// d_out = float[1049088]: c_t[256] r_t[256] new_mem[1048576].
// scr = out + 512: transpose fills new_mem during K1 (skips pxy column).
#define FLAT  238144      // 64*61*61
#define NB_R1 931

// ws float offsets (ws path)
#define W_C2   0          // 246016
#define W_P1   246016     // 119168 -> 365184
#define W_RT   365184     // 256
#define W_ST   365440     // 256
#define W_QT   365696     // 256
#define W_QTA  365952     // 256
#define W_STAT 366208     // 128 (64 x {max,expsum})
#define W_PC   366336     // 16384 (64 x 256) unnormalized partial PV
#define W_WARM 382720     // 16
#define W_D    382736     // 256 precomputed d-GEMV
#define W_SINK 382992     // 128 prefetch sinks
#define W_C1P  383120     // 1048576 conv1 chunk partials [8][32][4096]
#define W_END  1431696

// scr float offsets (fallback path; transpose runs LAST, separately)
#define F_C2   140416
#define F_P1   386432     // -> 505600
#define F_RT   505600
#define F_ST   505856
#define F_QT   506112
#define F_QTA  506368
#define F_STAT 510464
#define F_PC   510592     // -> 526976

__device__ __forceinline__ int read_idx(const int* p) {
    unsigned int u = (unsigned int)*p;
    int ex = (int)((u >> 23) & 0xFF);
    int v;
    if (ex >= 118 && ex <= 140) {
        union { unsigned int i; float f; } c; c.i = u;
        v = (int)(c.f + 0.5f);
    } else {
        v = (int)u;
    }
    return v < 0 ? 0 : (v > 63 ? 63 : v);
}

// ---- K1 "front": mode 1 (ws): [0..511]=conv1, [512..767]=transpose,
//      [768]=st, [769]=qta, [770..783]=warm. mode 0 (fb): all conv1.
__global__ __launch_bounds__(256) void k_front(const float* __restrict__ mem,
                                               const float* __restrict__ k1,
                                               float* __restrict__ c1p,
                                               const int* __restrict__ px,
                                               const int* __restrict__ py,
                                               float* __restrict__ outm,
                                               const float* __restrict__ inp,
                                               const float* __restrict__ rec,
                                               const float* __restrict__ ck,
                                               const float* __restrict__ d2,
                                               float* __restrict__ st,
                                               float* __restrict__ qta,
                                               float* __restrict__ warm,
                                               int mode) {
    __shared__ __align__(16) float SM[12576];   // conv1: sm(3360)+sk(9216)
    int t = threadIdx.x;
    int bid = blockIdx.x;
    if (mode == 1 && bid >= 512) {
        if (bid < 768) {
            int tu = bid - 512;
            float* tile = SM;                   // [64][65]
            int p0 = (tu & 63) * 64;
            int u0 = (tu >> 6) * 64;
            int x = read_idx(px), y = read_idx(py);
            int pxy = x * 64 + y;
            int lane = t & 63, grp = t >> 6;
            for (int r = 0; r < 16; ++r) {
                int pr = grp + r * 4;
                tile[pr * 65 + lane] = mem[(size_t)(p0 + pr) * 256 + u0 + lane];
            }
            __syncthreads();
            for (int r = 0; r < 16; ++r) {
                int ur = grp + r * 4;
                if (p0 + lane != pxy)
                    outm[(size_t)(u0 + ur) * 4096 + p0 + lane] =
                        tile[lane * 65 + ur];
            }
        } else if (bid == 768) {
            float sv = 0.f;
            #pragma unroll 16
            for (int k = 0; k < 128; ++k) sv += inp[k] * rec[k * 256 + t];
            st[t] = sv;
        } else if (bid == 769) {
            float q = 0.f;
            #pragma unroll 16
            for (int k = 0; k < 128; ++k) q += inp[k] * ck[k * 256 + t];
            qta[t] = q;
        } else {
            int wu = bid - 770;                 // 0..13
            float a = 0.f;
            for (int k = 0; k < 12; ++k) {
                int j = (wu * 256 + t) + k * 3584;
                if (j < 40960) {
                    float4 v;
                    if (j < 8192)        v = ((const float4*)d2 )[j];
                    else if (j < 24576)  v = ((const float4*)rec)[j];
                    else                 v = ((const float4*)ck )[j - 16384];
                    a += v.x + v.y + v.z + v.w;
                }
            }
            SM[t] = a;
            __syncthreads();
            if (t == 0) {
                float s = 0.f;
                for (int i = 0; i < 256; ++i) s += SM[i];
                warm[wu] = s;
            }
        }
        return;
    }
    // ---- conv1 unit
    float* sm = SM;                 // [32][105]
    float* sk = SM + 3360;          // [9][32][32]
    int th = ((bid & 63) >> 3) * 8;
    int tw = (bid & 7) * 8;
    int chunk = bid >> 6;
    {
        float4 mv[4];
        #pragma unroll
        for (int k = 0; k < 4; ++k) {
            int u = t + k * 256;
            float4 v = make_float4(0.f, 0.f, 0.f, 0.f);
            if (u < 800) {
                int pix = u >> 3, c4 = u & 7;
                int hh = th - 1 + pix / 10;
                int ww = tw - 1 + pix % 10;
                if ((unsigned)hh < 64u && (unsigned)ww < 64u)
                    v = *(const float4*)(mem + (size_t)(hh * 64 + ww) * 256
                                             + chunk * 32 + c4 * 4);
            }
            mv[k] = v;
        }
        #pragma unroll
        for (int k = 0; k < 4; ++k) {
            int u = t + k * 256;
            if (u < 800) {
                int pix = u >> 3, c4 = u & 7;
                int ib = c4 * 4;
                sm[(ib    ) * 105 + pix] = mv[k].x;
                sm[(ib + 1) * 105 + pix] = mv[k].y;
                sm[(ib + 2) * 105 + pix] = mv[k].z;
                sm[(ib + 3) * 105 + pix] = mv[k].w;
            }
        }
    }
    {
        float4 kv[9];
        #pragma unroll
        for (int k = 0; k < 9; ++k)
            kv[k] = ((const float4*)(k1 + (size_t)k * 8192
                                        + (size_t)chunk * 1024))[t];
        #pragma unroll
        for (int k = 0; k < 9; ++k)
            *(float4*)&sk[k * 1024 + t * 4] = kv[k];
    }
    __syncthreads();
    int lh = (t & 63) >> 3, lw = t & 7, og = t >> 6;
    float acc[8];
    #pragma unroll
    for (int j = 0; j < 8; ++j) acc[j] = 0.f;
    for (int dh = 0; dh < 3; ++dh)
        for (int dw = 0; dw < 3; ++dw) {
            int pixb = (lh + dh) * 10 + (lw + dw);
            const float* kt = sk + (dh * 3 + dw) * 1024 + og * 8;
            #pragma unroll 4
            for (int i = 0; i < 32; ++i) {
                float m = sm[i * 105 + pixb];
                float4 ka = *(const float4*)(kt + i * 32);
                float4 kb = *(const float4*)(kt + i * 32 + 4);
                acc[0] += m * ka.x; acc[1] += m * ka.y;
                acc[2] += m * ka.z; acc[3] += m * ka.w;
                acc[4] += m * kb.x; acc[5] += m * kb.y;
                acc[6] += m * kb.z; acc[7] += m * kb.w;
            }
        }
    int p = (th + lh) * 64 + tw + lw;
    float* dst = c1p + (size_t)chunk * 131072 + (size_t)(og * 8) * 4096 + p;
    #pragma unroll
    for (int j = 0; j < 8; ++j)
        dst[(size_t)j * 4096] = acc[j];
}

// ---- fallback only: compact 8 chunk partials (ascending order)
__global__ __launch_bounds__(256) void k_c1red(float* __restrict__ c1p) {
    int idx = blockIdx.x * 256 + threadIdx.x;
    float s = 0.f;
    #pragma unroll
    for (int c = 0; c < 8; ++c) s += c1p[(size_t)c * 131072 + idx];
    c1p[idx] = s;
}

// ---- K2: conv2 + (mode 1) d-GEMV block + d1 prefetch blocks.
// grid (64, 6) mode1 / (64, 4) mode0. y<4: conv2. (0,4): d-GEMV.
// other y>=4: prefetch first ~50MB of d1 into L3 (8-deep batched).
__global__ __launch_bounds__(256) void k_conv2(const float* __restrict__ c1p,
                                               const float* __restrict__ k2,
                                               float* __restrict__ c2,
                                               int nchunks,
                                               const float* __restrict__ d1,
                                               const float* __restrict__ mem,
                                               const float* __restrict__ st,
                                               const float* __restrict__ rec,
                                               const int* __restrict__ px,
                                               const int* __restrict__ py,
                                               float* __restrict__ dout,
                                               float* __restrict__ sink) {
    __shared__ __align__(16) float smu[32 * 104 > 512 ? 32 * 104 : 512];
    __shared__ __align__(16) float sk2[9 * 32 * 16];
    int t = threadIdx.x;
    if (blockIdx.y >= 4) {
        if (blockIdx.y == 4 && blockIdx.x == 0) {
            // ---- d-GEMV: d[t] = sum_k (mem[pxy*256+k]-st[k])*rec[(128+k)*256+t]
            float* s_diff = smu;
            int x = read_idx(px), y = read_idx(py);
            int pxy = x * 64 + y;
            s_diff[t] = mem[(size_t)pxy * 256 + t] - st[t];
            __syncthreads();
            float d = 0.f;
            #pragma unroll 16
            for (int k = 0; k < 256; ++k)
                d += s_diff[k] * rec[(128 + k) * 256 + t];
            dout[t] = d;
        } else {
            // ---- prefetch: 127 blocks x 256 thr x 96 f4 = 49.9 MB of d1
            int pb = (blockIdx.y - 4) * 64 + blockIdx.x - 1;   // 0..126
            const float4* dp = (const float4*)d1;
            float a = 0.f;
            #pragma unroll
            for (int rr = 0; rr < 12; ++rr) {
                float4 v[8];
                #pragma unroll
                for (int k = 0; k < 8; ++k) {
                    size_t j = (size_t)(pb * 256 + t)
                             + (size_t)(rr * 8 + k) * 32512;
                    v[k] = dp[j];
                }
                #pragma unroll
                for (int k = 0; k < 8; ++k)
                    a += v[k].x + v[k].y + v[k].z + v[k].w;
            }
            smu[t] = a;
            __syncthreads();
            if (t == 0) {
                float s = 0.f;
                for (int i = 0; i < 256; ++i) s += smu[i];
                sink[pb] = s;
            }
        }
        return;
    }
    float* sm = smu;
    int th = (blockIdx.x >> 3) * 8;
    int tw = (blockIdx.x & 7) * 8;
    int o0 = blockIdx.y * 16;
    if (nchunks == 8) {
        #pragma unroll 2
        for (int u = t; u < 3200; u += 256) {
            int i = u / 100;
            int pix = u % 100;
            int hh = th + pix / 10;
            int ww = tw + pix % 10;
            float v = 0.f;
            if (hh < 64 && ww < 64) {
                const float* p = c1p + (size_t)i * 4096 + hh * 64 + ww;
                float a0 = p[0];
                float a1 = p[131072];
                float a2 = p[2 * 131072];
                float a3 = p[3 * 131072];
                float a4 = p[4 * 131072];
                float a5 = p[5 * 131072];
                float a6 = p[6 * 131072];
                float a7 = p[7 * 131072];
                v = a0 + a1 + a2 + a3 + a4 + a5 + a6 + a7;
            }
            sm[i * 104 + pix] = v;
        }
    } else {
        for (int u = t; u < 3200; u += 256) {
            int i = u / 100;
            int pix = u % 100;
            int hh = th + pix / 10;
            int ww = tw + pix % 10;
            float v = 0.f;
            if (hh < 64 && ww < 64)
                v = c1p[(size_t)i * 4096 + hh * 64 + ww];
            sm[i * 104 + pix] = v;
        }
    }
    {
        float4 kv[5];
        #pragma unroll
        for (int k = 0; k < 5; ++k) {
            int u = t + k * 256;
            if (u < 1152) {
                int tap = u >> 7, r = u & 127;
                int i = r >> 2, o4 = r & 3;
                kv[k] = *(const float4*)(k2 + (size_t)tap * 2048 + i * 64
                                            + o0 + o4 * 4);
            }
        }
        #pragma unroll
        for (int k = 0; k < 5; ++k) {
            int u = t + k * 256;
            if (u < 1152) {
                int tap = u >> 7, r = u & 127;
                int i = r >> 2, o4 = r & 3;
                *(float4*)&sk2[tap * 512 + i * 16 + o4 * 4] = kv[k];
            }
        }
    }
    __syncthreads();
    int pix = t & 63;
    int lh = pix >> 3, lw = pix & 7, og = t >> 6;
    float acc[4] = {0.f, 0.f, 0.f, 0.f};
    for (int dh = 0; dh < 3; ++dh)
        for (int dw = 0; dw < 3; ++dw) {
            int pixb = (lh + dh) * 10 + (lw + dw);
            const float* kt = sk2 + (dh * 3 + dw) * 512 + og * 4;
            #pragma unroll 8
            for (int i = 0; i < 32; ++i) {
                float m = sm[i * 104 + pixb];
                float4 kv = *(const float4*)(kt + i * 16);
                acc[0] += m * kv.x; acc[1] += m * kv.y;
                acc[2] += m * kv.z; acc[3] += m * kv.w;
            }
        }
    int h = th + lh, w = tw + lw;
    if (h < 62 && w < 62) {
        #pragma unroll
        for (int j = 0; j < 4; ++j)
            c2[(size_t)(o0 + og * 4 + j) * 3844 + h * 62 + w] = acc[j];
    }
}

// ---- K3: pure r1p (931 blocks): pool + dense1 partials
__global__ __launch_bounds__(256) void k_r1p(const float* __restrict__ c2,
                                             const float* __restrict__ d1,
                                             float* __restrict__ p1) {
    __shared__ __align__(16) float SM[4160];
    int t = threadIdx.x;
    int fb = blockIdx.x;
    float* pl   = SM;
    float* sred = SM + 256;
    int f0 = fb * 256;
    int fmax = FLAT - f0; if (fmax > 256) fmax = 256;
    for (int s = t; s < fmax; s += 256) {
        int f = f0 + s;
        int o = f / 3721;
        int r = f % 3721;
        int h = r / 61, w = r % 61;
        const float* b = c2 + (size_t)o * 3844 + h * 62 + w;
        pl[s] = 0.25f * (b[0] + b[1] + b[62] + b[63]);
    }
    __syncthreads();
    int jq = t & 31, g = t >> 5;
    float4 a = make_float4(0.f, 0.f, 0.f, 0.f);
    if (fmax == 256) {
        #pragma unroll 16
        for (int it = 0; it < 32; ++it) {
            int s = g + it * 8;
            float m = pl[s];
            float4 dv = *(const float4*)(d1 + (size_t)(f0 + s) * 128 + jq * 4);
            a.x += m * dv.x; a.y += m * dv.y; a.z += m * dv.z; a.w += m * dv.w;
        }
    } else {
        for (int s = g; s < fmax; s += 8) {
            float m = pl[s];
            float4 dv = *(const float4*)(d1 + (size_t)(f0 + s) * 128 + jq * 4);
            a.x += m * dv.x; a.y += m * dv.y; a.z += m * dv.z; a.w += m * dv.w;
        }
    }
    *(float4*)&sred[(g * 32 + jq) * 4] = a;
    __syncthreads();
    if (t < 32) {
        float4 s4 = make_float4(0.f, 0.f, 0.f, 0.f);
        #pragma unroll
        for (int gg = 0; gg < 8; ++gg) {
            float4 v = *(const float4*)&sred[(gg * 32 + t) * 4];
            s4.x += v.x; s4.y += v.y; s4.z += v.z; s4.w += v.w;
        }
        *(float4*)(p1 + (size_t)fb * 128 + t * 4) = s4;
    }
}

// ---- K4: fused r1 reduce + rt + qt-tail. haveAux=1: st/qta precomputed.
__global__ __launch_bounds__(1024) void k_fused(const float* __restrict__ p1,
                                                const float* __restrict__ d2,
                                                const float* __restrict__ inp,
                                                const float* __restrict__ ck,
                                                const float* __restrict__ rec,
                                                const float* __restrict__ qta,
                                                float* __restrict__ rt,
                                                float* __restrict__ qt,
                                                float* __restrict__ st,
                                                int haveAux) {
    __shared__ float p2s[8][128];
    __shared__ float s_r1[128], s_in[128], s_rt[256];
    int t = threadIdx.x;
    int j = t & 127, part = t >> 7;
    int b0 = part * 117;
    int b1 = b0 + 117; if (b1 > NB_R1) b1 = NB_R1;
    float s = 0.f;
    #pragma unroll 8
    for (int b = b0; b < b1; ++b) s += p1[b * 128 + j];
    p2s[part][j] = s;
    if (t < 128) s_in[t] = inp[t];
    __syncthreads();
    if (t < 128) {
        float r = 0.f;
        #pragma unroll
        for (int c = 0; c < 8; ++c) r += p2s[c][t];
        s_r1[t] = r;
    }
    __syncthreads();
    if (t < 256) {
        float a = 0.f;
        #pragma unroll 16
        for (int k = 0; k < 128; ++k) a += s_r1[k] * d2[k * 256 + t];
        rt[t] = a; s_rt[t] = a;
        if (!haveAux) {
            float sv = 0.f;
            #pragma unroll 16
            for (int k = 0; k < 128; ++k) sv += s_in[k] * rec[k * 256 + t];
            st[t] = sv;
        }
    }
    __syncthreads();
    if (t < 256) {
        float q;
        if (haveAux) {
            q = qta[t];
        } else {
            q = 0.f;
            #pragma unroll 16
            for (int k = 0; k < 128; ++k) q += s_in[k] * ck[k * 256 + t];
        }
        #pragma unroll 16
        for (int k = 0; k < 256; ++k) q += s_rt[k] * ck[(128 + k) * 256 + t];
        qt[t] = q;
    }
}

// ---- K5: scores + stats + UNNORMALIZED partial PV (64 blocks, 64 rows each)
__global__ __launch_bounds__(256) void k_scores(const float* __restrict__ qt,
                                                const float* __restrict__ mem,
                                                float* __restrict__ stat,
                                                float* __restrict__ pc) {
    __shared__ float q[256];
    __shared__ float rowv[64], aL[64];
    __shared__ float mbS;
    int t = threadIdx.x;
    int bid = blockIdx.x;
    q[t] = qt[t];
    __syncthreads();
    int wave = t >> 6, lane = t & 63;
    float qx = q[lane * 4], qy = q[lane * 4 + 1],
          qz = q[lane * 4 + 2], qw = q[lane * 4 + 3];
    int p0 = bid * 64;
    for (int r = 0; r < 16; ++r) {
        int p = p0 + wave * 16 + r;
        float4 m = *(const float4*)(mem + (size_t)p * 256 + lane * 4);
        float acc = m.x * qx + m.y * qy + m.z * qz + m.w * qw;
        for (int off = 32; off; off >>= 1) acc += __shfl_down(acc, off);
        if (lane == 0) rowv[wave * 16 + r] = acc;
    }
    __syncthreads();
    if (t == 0) {
        float mb = rowv[0];
        for (int i = 1; i < 64; ++i) mb = fmaxf(mb, rowv[i]);
        mbS = mb;
    }
    __syncthreads();
    if (t < 64) aL[t] = expf(rowv[t] - mbS);
    __syncthreads();
    if (t == 0) {
        float sb = 0.f;
        for (int i = 0; i < 64; ++i) sb += aL[i];
        stat[bid * 2]     = mbS;
        stat[bid * 2 + 1] = sb;
    }
    float acc = 0.f;
    #pragma unroll 16
    for (int pp = 0; pp < 64; ++pp)
        acc += aL[pp] * mem[(size_t)(p0 + pp) * 256 + t];
    pc[bid * 256 + t] = acc;
}

// ---- K6: final. haveD=1: d precomputed (conv2 extra block).
__global__ __launch_bounds__(256) void k_final(const float* __restrict__ rt,
                                               const float* __restrict__ st,
                                               const float* __restrict__ stat,
                                               const float* __restrict__ pc,
                                               const float* __restrict__ mem,
                                               const float* __restrict__ rec,
                                               const int* __restrict__ px,
                                               const int* __restrict__ py,
                                               const float* __restrict__ dpre,
                                               float* __restrict__ out,
                                               int haveD) {
    __shared__ float s_diff[256], red[256];
    __shared__ float sm_[64], wb[64], aux[2];
    int t = threadIdx.x;
    int x = read_idx(px), y = read_idx(py);
    int pxy = x * 64 + y;
    if (t < 64) sm_[t] = stat[t * 2];
    __syncthreads();
    if (t == 0) {
        float M = sm_[0];
        for (int i = 1; i < 64; ++i) M = fmaxf(M, sm_[i]);
        float S = 0.f;
        for (int i = 0; i < 64; ++i) S += stat[i * 2 + 1] * expf(sm_[i] - M);
        aux[0] = M; aux[1] = 1.f / S;
    }
    __syncthreads();
    if (t < 64) wb[t] = expf(sm_[t] - aux[0]) * aux[1];
    __syncthreads();
    float ctv = 0.f;
    #pragma unroll 16
    for (int b = 0; b < 64; ++b) ctv += pc[b * 256 + t] * wb[b];
    float stv = st[t], rtv = rt[t];
    float memt = mem[(size_t)pxy * 256 + t];
    red[t] = stv * rtv; __syncthreads();
    for (int s = 128; s; s >>= 1) { if (t < s) red[t] += red[t + s]; __syncthreads(); }
    float gimp = red[0]; __syncthreads();
    red[t] = stv * ctv; __syncthreads();
    for (int s = 128; s; s >>= 1) { if (t < s) red[t] += red[t + s]; __syncthreads(); }
    float limp = red[0];
    float d;
    if (haveD) {
        d = dpre[t];
    } else {
        s_diff[t] = memt - stv;
        __syncthreads();
        d = 0.f;
        #pragma unroll 16
        for (int k = 0; k < 256; ++k)
            d += s_diff[k] * rec[(128 + k) * 256 + t];
    }
    float frac = limp / (limp + gimp);
    out[t] = ctv;
    out[256 + t] = rtv;
    out[512 + (size_t)t * 4096 + pxy] = memt + frac * d;
}

// ---- fallback only: standalone transpose (runs LAST on scr path)
__global__ __launch_bounds__(256) void k_transpose(const float* __restrict__ mem,
                                                   const int* __restrict__ px,
                                                   const int* __restrict__ py,
                                                   float* __restrict__ outm) {
    __shared__ float tile[64][65];
    int t = threadIdx.x;
    int p0 = blockIdx.x * 64;
    int u0 = blockIdx.y * 64;
    int x = read_idx(px), y = read_idx(py);
    int pxy = x * 64 + y;
    int lane = t & 63, grp = t >> 6;
    for (int r = 0; r < 16; ++r) {
        int pr = grp + r * 4;
        tile[pr][lane] = mem[(size_t)(p0 + pr) * 256 + u0 + lane];
    }
    __syncthreads();
    for (int r = 0; r < 16; ++r) {
        int ur = grp + r * 4;
        if (p0 + lane != pxy)
            outm[(size_t)(u0 + ur) * 4096 + p0 + lane] = tile[lane][ur];
    }
}

extern "C" void kernel_launch(void* const* d_in, const int* in_sizes, int n_in,
                              void* d_out, int out_size, void* d_ws, size_t ws_size,
                              hipStream_t stream) {
    const float* inp = (const float*)d_in[0];
    const float* mem = (const float*)d_in[1];
    const float* k1  = (const float*)d_in[2];
    const float* k2  = (const float*)d_in[3];
    const float* d1  = (const float*)d_in[4];
    const float* d2  = (const float*)d_in[5];
    const float* ck  = (const float*)d_in[6];
    const float* rec = (const float*)d_in[7];
    const int* px = (const int*)d_in[8];
    const int* py = (const int*)d_in[9];
    float* out = (float*)d_out;
    float* scr = out + 512;
    float* ws  = (float*)d_ws;

    bool useWs = (ws != nullptr) && (ws_size >= (size_t)W_END * sizeof(float));

    if (useWs) {
        k_front<<<784, 256, 0, stream>>>(mem, k1, ws + W_C1P, px, py, scr,
                                         inp, rec, ck, d2,
                                         ws + W_ST, ws + W_QTA, ws + W_WARM, 1);
        k_conv2<<<dim3(64, 6), 256, 0, stream>>>(ws + W_C1P, k2, ws + W_C2, 8,
                                                 d1, mem, ws + W_ST, rec,
                                                 px, py, ws + W_D, ws + W_SINK);
        k_r1p<<<NB_R1, 256, 0, stream>>>(ws + W_C2, d1, ws + W_P1);
        k_fused<<<1, 1024, 0, stream>>>(ws + W_P1, d2, inp, ck, rec,
                                        ws + W_QTA, ws + W_RT, ws + W_QT,
                                        ws + W_ST, 1);
        k_scores<<<64, 256, 0, stream>>>(ws + W_QT, mem, ws + W_STAT,
                                         ws + W_PC);
        k_final<<<1, 256, 0, stream>>>(ws + W_RT, ws + W_ST, ws + W_STAT,
                                       ws + W_PC, mem, rec, px, py,
                                       ws + W_D, out, 1);
    } else {
        k_front<<<512, 256, 0, stream>>>(mem, k1, scr, px, py, scr,
                                         inp, rec, ck, d2,
                                         scr + F_ST, scr + F_QTA,
                                         scr + F_PC + 16384, 0);
        k_c1red<<<512, 256, 0, stream>>>(scr);
        k_conv2<<<dim3(64, 4), 256, 0, stream>>>(scr, k2, scr + F_C2, 1,
                                                 d1, mem, scr + F_ST, rec,
                                                 px, py, scr + F_PC + 16400,
                                                 scr + F_PC + 16656);
        k_r1p<<<NB_R1, 256, 0, stream>>>(scr + F_C2, d1, scr + F_P1);
        k_fused<<<1, 1024, 0, stream>>>(scr + F_P1, d2, inp, ck, rec,
                                        scr + F_QTA, scr + F_RT, scr + F_QT,
                                        scr + F_ST, 0);
        k_scores<<<64, 256, 0, stream>>>(scr + F_QT, mem, scr + F_STAT,
                                         scr + F_PC);
        k_final<<<1, 256, 0, stream>>>(scr + F_RT, scr + F_ST, scr + F_STAT,
                                       scr + F_PC, mem, rec, px, py,
                                       scr, out, 0);
        k_transpose<<<dim3(64, 4), 256, 0, stream>>>(mem, px, py, out + 512);
    }
}